// Round 9
// baseline (339.783 us; speedup 1.0000x reference)
//
#include <hip/hip_runtime.h>
#include <math.h>

#define B_ 64
#define T_ 1024
#define D_ 768
#define A_ 128

typedef __attribute__((ext_vector_type(4))) float f32x4;
typedef __attribute__((ext_vector_type(8))) short s16x8;
typedef __attribute__((ext_vector_type(4))) short s16x4;

__device__ inline short f2b(float f) {
  union { float f; unsigned u; } v; v.f = f;
  unsigned r = (v.u + 0x7FFFu + ((v.u >> 16) & 1u)) >> 16;
  return (short)r;
}
__device__ inline float b2f(short s) {
  union { unsigned u; float f; } v; v.u = ((unsigned)(unsigned short)s) << 16;
  return v.f;
}

__device__ inline void gll16(const void* g, const void* lds) {
  __builtin_amdgcn_global_load_lds(
      (const __attribute__((address_space(1))) unsigned*)g,
      (__attribute__((address_space(3))) unsigned*)lds, 16, 0, 0);
}

// ---------------------------------------------------------------------------
// G4: persistent 256x256-tile, BK=64, 8-wave, 8-phase counted-vmcnt bf16 GEMM.
// out[s,d] = (sum_t E[s,t]*xt[d,t]) / rowsum[s].
// Grid = 4*nb blocks; each block processes 3 CONSECUTIVE logical tiles
// (same batch, shared St/xt panels -> L2 reuse). Per tile:
//   main loop -> epilogue stores -> stage NEXT tile's prologue.
// Stores are issued BEFORE the next prologue loads; vmcnt retires in-order
// (m135), so the next loop-head vmcnt(6) waits stores (L2-speed) + the 8
// oldest loads = next tile fully landed. Prologue latency hides under
// epilogue; MFMA warm across tiles.
// T2 st-swizzle (SQ_LDS_BANK_CONFLICT=0, verified R5). 120 VGPR, no spill.
// ---------------------------------------------------------------------------
__global__ __launch_bounds__(512, 2)
void g4_div(const short* __restrict__ Ag, const short* __restrict__ Bg,
            const float* __restrict__ Rs, float* __restrict__ Cg) {
  __shared__ __align__(16) short AS[2][16384];
  __shared__ __align__(16) short BS[2][16384];
  // bijective XCD swizzle on block id
  unsigned nwg = gridDim.x;
  unsigned L = blockIdx.x;
  unsigned xcd = L & 7u, base = L >> 3;
  unsigned q = nwg >> 3, r = nwg & 7u;
  unsigned lb = (xcd < r ? xcd * (q + 1) : r * (q + 1) + (xcd - r) * q) + base;

  const int tid = threadIdx.x;
  const int w = tid >> 6, lane = tid & 63;
  const int wr = w >> 2, wc = w & 3;
  const int lr = lane & 15, lq = lane >> 4;
  const int swzk = (lane & 7) ^ ((lane >> 3) & 7);   // source pre-swizzle
  const int abase = (wr * 128 + lr) * 64;
  const int bbase = (wc * 64 + lr) * 64;
  const int sx = lr & 7;
  const int sl0 = (lq ^ sx) * 8;          // kk=0 swizzled slot (shorts)
  const int sl1 = ((4 + lq) ^ sx) * 8;    // kk=1

  // mutable current-tile state
  const short* Ab; const short* Bb; int m0, n0, bz;
  auto decode = [&](int idt) {
    bz = idt / 12;
    int rm = idt - bz * 12;
    m0 = (rm / 3) * 256;
    n0 = (rm - (rm / 3) * 3) * 256;
    Ab = Ag + (size_t)bz * (T_ * T_);
    Bb = Bg + (size_t)bz * (D_ * T_);
  };

#define STG(dst, src, r0, kt)                                                  \
  { _Pragma("unroll")                                                          \
    for (int jj = 0; jj < 2; ++jj) {                                           \
      int rr = jj * 64 + w * 8 + (lane >> 3);                                  \
      gll16((src) + (size_t)((r0) + rr) * 1024 + (kt) + swzk * 8,              \
            (dst) + jj * 4096 + w * 512);                                      \
    } }

// stage tile-k-tile pair (prologue): tile0 full + tile1 B0,B1,A0 (14 loads)
#define PRO()                                                                  \
  {                                                                            \
    STG(&BS[0][0],    Bb, n0,       0);                                        \
    STG(&BS[0][8192], Bb, n0 + 128, 0);                                        \
    STG(&AS[0][0],    Ab, m0,       0);                                        \
    STG(&AS[0][8192], Ab, m0 + 128, 0);                                        \
    STG(&BS[1][0],    Bb, n0,       64);                                       \
    STG(&BS[1][8192], Bb, n0 + 128, 64);                                       \
    STG(&AS[1][0],    Ab, m0,       64);                                       \
  }

#define PHASE(P, Q, VM, STAGE)                                                 \
  {                                                                            \
    s16x8 a0_ = *(const s16x8*)&AS[P][abase + (2 * (Q)) * 1024 + sl0];         \
    s16x8 a1_ = *(const s16x8*)&AS[P][abase + (2 * (Q)) * 1024 + sl1];         \
    s16x8 a2_ = *(const s16x8*)&AS[P][abase + (2 * (Q) + 1) * 1024 + sl0];     \
    s16x8 a3_ = *(const s16x8*)&AS[P][abase + (2 * (Q) + 1) * 1024 + sl1];     \
    if ((Q) == 0) {                                                            \
      _Pragma("unroll")                                                        \
      for (int nf = 0; nf < 4; ++nf) {                                         \
        bq[nf][0] = *(const s16x8*)&BS[P][bbase + nf * 1024 + sl0];            \
        bq[nf][1] = *(const s16x8*)&BS[P][bbase + nf * 1024 + sl1];            \
      }                                                                        \
    }                                                                          \
    STAGE;                                                                     \
    VM;                                                                        \
    __builtin_amdgcn_s_barrier();                                              \
    asm volatile("s_waitcnt lgkmcnt(0)" ::: "memory");                         \
    __builtin_amdgcn_s_setprio(1);                                             \
    _Pragma("unroll")                                                          \
    for (int nf = 0; nf < 4; ++nf) {                                           \
      acc[2*(Q)][nf]   = __builtin_amdgcn_mfma_f32_16x16x32_bf16(a0_, bq[nf][0], acc[2*(Q)][nf], 0, 0, 0);   \
      acc[2*(Q)+1][nf] = __builtin_amdgcn_mfma_f32_16x16x32_bf16(a2_, bq[nf][0], acc[2*(Q)+1][nf], 0, 0, 0); \
    }                                                                          \
    _Pragma("unroll")                                                          \
    for (int nf = 0; nf < 4; ++nf) {                                           \
      acc[2*(Q)][nf]   = __builtin_amdgcn_mfma_f32_16x16x32_bf16(a1_, bq[nf][1], acc[2*(Q)][nf], 0, 0, 0);   \
      acc[2*(Q)+1][nf] = __builtin_amdgcn_mfma_f32_16x16x32_bf16(a3_, bq[nf][1], acc[2*(Q)+1][nf], 0, 0, 0); \
    }                                                                          \
    __builtin_amdgcn_s_setprio(0);                                             \
    __builtin_amdgcn_s_barrier();                                              \
  }

#define VM6 asm volatile("s_waitcnt vmcnt(6)" ::: "memory")
#define VM0 asm volatile("s_waitcnt vmcnt(0)" ::: "memory")
#define NOP (void)0

  decode((int)lb * 3);
  PRO();                                  // first tile's prologue

#pragma unroll 1
  for (int tt = 0; tt < 3; ++tt) {
    f32x4 acc[8][4] = {};
    s16x8 bq[4][2];

    VM6;                                  // stores(old)+8 oldest loads retired
    __builtin_amdgcn_s_barrier();

    for (int j = 0; j < 7; ++j) {
      const int kb = j * 128;
      PHASE(0, 0, NOP, STG(&AS[1][8192], Ab, m0 + 128, kb + 64));
      PHASE(0, 1, NOP, STG(&BS[0][0],    Bb, n0,       kb + 128));
      PHASE(0, 2, NOP, STG(&BS[0][8192], Bb, n0 + 128, kb + 128));
      PHASE(0, 3, VM6, STG(&AS[0][0],    Ab, m0,       kb + 128));
      PHASE(1, 0, NOP, STG(&AS[0][8192], Ab, m0 + 128, kb + 128));
      PHASE(1, 1, NOP, STG(&BS[1][0],    Bb, n0,       kb + 192));
      PHASE(1, 2, NOP, STG(&BS[1][8192], Bb, n0 + 128, kb + 192));
      PHASE(1, 3, VM6, STG(&AS[1][0],    Ab, m0,       kb + 192));
    }
    // final iteration: tiles 14 (buf0), 15 (buf1); only t15.A1 left to stage
    PHASE(0, 0, NOP, STG(&AS[1][8192], Ab, m0 + 128, 960));
    PHASE(0, 1, NOP, NOP);
    PHASE(0, 2, NOP, NOP);
    PHASE(0, 3, VM0, NOP);
    PHASE(1, 0, NOP, NOP);
    PHASE(1, 1, NOP, NOP);
    PHASE(1, 2, NOP, NOP);
    PHASE(1, 3, NOP, NOP);
    // all waves past LDS reads (final phase ends with barrier); LDS free

    // epilogue: scale by 1/rowsum[s], store (uses CURRENT tile's m0/n0/bz)
    {
      const float* rsb = Rs + (size_t)bz * T_;
      float* Cb = Cg + (size_t)bz * (T_ * D_);
#pragma unroll
      for (int mf = 0; mf < 8; ++mf) {
        f32x4 rsv = *(const f32x4*)&rsb[m0 + wr * 128 + mf * 16 + lq * 4];
        f32x4 inv;
#pragma unroll
        for (int qq = 0; qq < 4; ++qq) {
          float iv;
          asm("v_rcp_f32 %0, %1" : "=v"(iv) : "v"(rsv[qq]));
          inv[qq] = iv;
        }
#pragma unroll
        for (int nf = 0; nf < 4; ++nf) {
          int m = m0 + wr * 128 + mf * 16 + lq * 4;
          int n = n0 + wc * 64 + nf * 16 + lr;
#pragma unroll
          for (int qq = 0; qq < 4; ++qq)
            Cb[(size_t)(m + qq) * D_ + n] = acc[mf][nf][qq] * inv[qq];
        }
      }
    }
    // stage next tile's prologue AFTER stores (in-order vmcnt retirement)
    if (tt < 2) {
      decode((int)lb * 3 + tt + 1);
      PRO();
    }
  }

#undef STG
#undef PRO
#undef PHASE
#undef VM6
#undef VM0
#undef NOP
}

// ---------------------------------------------------------------------------
// bf16 MFMA GEMM (single-buffer 128x128, for G1/G2): C = A @ Bt^T
// EXPSUM (G2): write exp(acc) bf16 AND atomically accumulate row-sums of the
// rounded exp values into Rs[n] (device-scope atomics, 16 adds per row).
// ---------------------------------------------------------------------------
template<bool BF32, bool TANH_, bool WT, bool OB16, bool EXPSUM>
__global__ __launch_bounds__(256, 2)
void gemm_bt(const short* __restrict__ Ab, const void* __restrict__ Bv,
             void* __restrict__ Cv, float* __restrict__ Rs,
             int M, int N, int K,
             long sA, long sB, long sC, int gx, int gy) {
  __shared__ __align__(16) short As[128 * 64];
  __shared__ __align__(16) short Bs[128 * 64];
  unsigned nwg = gridDim.x;
  unsigned L = blockIdx.x;
  unsigned xcd = L & 7u, base = L >> 3;
  unsigned q = nwg >> 3, r = nwg & 7u;
  unsigned id = (xcd < r ? xcd * (q + 1) : r * (q + 1) + (xcd - r) * q) + base;
  const int gxy = gx * gy;
  const int bz = id / gxy;
  const int rem = id - bz * gxy;
  const int by = rem / gx;
  const int bx = rem - by * gx;

  const int tid = threadIdx.x;
  const int w = tid >> 6, lane = tid & 63;
  const int n0 = bx * 128, m0 = by * 128;
  const int wr = w >> 1, wc = w & 1;
  const int lr = lane & 15, lq = lane >> 4;
  const short* A = Ab + (size_t)sA * bz;
  const short* Bb16 = nullptr; const float* Bf32 = nullptr;
  if (BF32) Bf32 = (const float*)Bv + (size_t)sB * bz;
  else      Bb16 = (const short*)Bv + (size_t)sB * bz;

  f32x4 acc[4][4] = {};
  const int r8 = lane >> 3, c8 = lane & 7;

  for (int k0 = 0; k0 < K; k0 += 64) {
    __syncthreads();
#pragma unroll
    for (int i = 0; i < 4; ++i) {
      int chunk = w * 4 + i;
      int row = chunk * 8 + r8;
      gll16(A + (size_t)(m0 + row) * K + k0 + c8 * 8, As + chunk * 512);
    }
    if (!BF32) {
#pragma unroll
      for (int i = 0; i < 4; ++i) {
        int chunk = w * 4 + i;
        int row = chunk * 8 + r8;
        gll16(Bb16 + (size_t)(n0 + row) * K + k0 + c8 * 8, Bs + chunk * 512);
      }
    } else {
#pragma unroll
      for (int u = 0; u < 4; ++u) {
        int c = tid * 4 + u;
        int row = c >> 3, k8 = c & 7;
        const float* gp = Bf32 + (size_t)(n0 + row) * K + k0 + k8 * 8;
        float4 f0 = *(const float4*)gp;
        float4 f1 = *(const float4*)(gp + 4);
        s16x8 p;
        p[0] = f2b(f0.x); p[1] = f2b(f0.y); p[2] = f2b(f0.z); p[3] = f2b(f0.w);
        p[4] = f2b(f1.x); p[5] = f2b(f1.y); p[6] = f2b(f1.z); p[7] = f2b(f1.w);
        *(s16x8*)&Bs[row * 64 + k8 * 8] = p;
      }
    }
    __syncthreads();
#pragma unroll
    for (int kk = 0; kk < 2; ++kk) {
      s16x8 a[4], b[4];
#pragma unroll
      for (int mf = 0; mf < 4; ++mf)
        a[mf] = *(const s16x8*)&As[(wr * 64 + mf * 16 + lr) * 64 + kk * 32 + lq * 8];
#pragma unroll
      for (int nf = 0; nf < 4; ++nf)
        b[nf] = *(const s16x8*)&Bs[(wc * 64 + nf * 16 + lr) * 64 + kk * 32 + lq * 8];
#pragma unroll
      for (int mf = 0; mf < 4; ++mf)
#pragma unroll
        for (int nf = 0; nf < 4; ++nf)
          acc[mf][nf] = __builtin_amdgcn_mfma_f32_16x16x32_bf16(
              a[mf], b[nf], acc[mf][nf], 0, 0, 0);
    }
  }

  if (WT) {
    if (OB16) {
      short* C = (short*)Cv + (size_t)sC * bz;
      float psum[4] = {0.f, 0.f, 0.f, 0.f};
#pragma unroll
      for (int mf = 0; mf < 4; ++mf)
#pragma unroll
        for (int nf = 0; nf < 4; ++nf) {
          int mbase = m0 + wr * 64 + mf * 16 + lq * 4;
          int n = n0 + wc * 64 + nf * 16 + lr;
          s16x4 pk;
#pragma unroll
          for (int qq = 0; qq < 4; ++qq) {
            float v = acc[mf][nf][qq];
            if (TANH_) v = tanhf(v);
            if (EXPSUM) v = __expf(v);
            pk[qq] = f2b(v);
            if (EXPSUM) psum[nf] += b2f(pk[qq]);  // sum the ROUNDED values
          }
          *(s16x4*)(C + (size_t)n * M + mbase) = pk;
        }
      if (EXPSUM) {
        float* rs = Rs + (size_t)T_ * bz;
#pragma unroll
        for (int nf = 0; nf < 4; ++nf) {
          psum[nf] += __shfl_xor(psum[nf], 16);
          psum[nf] += __shfl_xor(psum[nf], 32);
        }
        if (lq == 0) {
#pragma unroll
          for (int nf = 0; nf < 4; ++nf)
            atomicAdd(&rs[n0 + wc * 64 + nf * 16 + lr], psum[nf]);
        }
      }
    } else {
      float* C = (float*)Cv + (size_t)sC * bz;
#pragma unroll
      for (int mf = 0; mf < 4; ++mf)
#pragma unroll
        for (int nf = 0; nf < 4; ++nf) {
          int mbase = m0 + wr * 64 + mf * 16 + lq * 4;
          int n = n0 + wc * 64 + nf * 16 + lr;
#pragma unroll
          for (int qq = 0; qq < 4; ++qq) {
            float v = acc[mf][nf][qq];
            if (TANH_) v = tanhf(v);
            C[(size_t)n * M + mbase + qq] = v;
          }
        }
    }
  } else {
    float* C = (float*)Cv + (size_t)sC * bz;
#pragma unroll
    for (int mf = 0; mf < 4; ++mf)
#pragma unroll
      for (int nf = 0; nf < 4; ++nf) {
        int m = m0 + wr * 64 + mf * 16 + lq * 4;
        int n = n0 + wc * 64 + nf * 16 + lr;
#pragma unroll
        for (int qq = 0; qq < 4; ++qq) {
          float v = acc[mf][nf][qq];
          if (TANH_) v = tanhf(v);
          C[(size_t)(m + qq) * N + n] = v;
        }
      }
  }
}

// ---------------------------------------------------------------------------
// transpose + fp32->bf16: src [z][R][C] fp32 -> dst [z][C][R] bf16. 64x64 tiles.
// LDS stride 65 + scalar ops: read AND write banks are 2-way max (free).
// (stride-68 float4 variant had 8-way read conflicts: banks (16i+4j+dr)%32.)
// ---------------------------------------------------------------------------
__global__ __launch_bounds__(256)
void transpose_cvt(const float* __restrict__ src, short* __restrict__ dst,
                   int R, int C) {
  __shared__ float sh[64][65];
  const int tid = threadIdx.x;
  const float* s = src + (size_t)blockIdx.z * R * C;
  short* d = dst + (size_t)blockIdx.z * R * C;
  const int r0 = blockIdx.y * 64, c0 = blockIdx.x * 64;
#pragma unroll
  for (int u = 0; u < 4; ++u) {
    int e = tid + u * 256;
    int rr = e >> 4, cc4 = (e & 15) * 4;
    float4 v = *(const float4*)&s[(size_t)(r0 + rr) * C + c0 + cc4];
    sh[rr][cc4 + 0] = v.x;
    sh[rr][cc4 + 1] = v.y;
    sh[rr][cc4 + 2] = v.z;
    sh[rr][cc4 + 3] = v.w;
  }
  __syncthreads();
#pragma unroll
  for (int u = 0; u < 4; ++u) {
    int e = tid + u * 256;
    int dr = e >> 4, tc4 = (e & 15) * 4;
    s16x4 pk;
#pragma unroll
    for (int j = 0; j < 4; ++j) pk[j] = f2b(sh[tc4 + j][dr]);
    *(s16x4*)&d[(size_t)(c0 + dr) * R + r0 + tc4] = pk;
  }
}

extern "C" void kernel_launch(void* const* d_in, const int* in_sizes, int n_in,
                              void* d_out, int out_size, void* d_ws, size_t ws_size,
                              hipStream_t stream) {
  const float* x  = (const float*)d_in[0];   // [B,T,D]
  const float* W1 = (const float*)d_in[1];   // [D,A]
  const float* W2 = (const float*)d_in[2];   // [A,T]
  float* out = (float*)d_out;                // [B,T,D] fp32

  // ws (shorts): xt[B,D,T] | W1t[A,D] | W2t[T,A] | H[B,T,A] | rs[B*T fp32] | St[nb,T,T]
  short* xt  = (short*)d_ws;
  short* W1t = xt + (size_t)B_ * D_ * T_;
  short* W2t = W1t + (size_t)A_ * D_;
  short* H   = W2t + (size_t)T_ * A_;
  float* rs  = (float*)(H + (size_t)B_ * T_ * A_);
  short* St  = (short*)(rs + (size_t)B_ * T_);
  size_t fixed_bytes = (size_t)((char*)St - (char*)xt);
  long avail = (long)ws_size - (long)fixed_bytes;
  long per_b = (long)T_ * T_ * sizeof(short);
  int chunk = (int)(avail > 0 ? avail / per_b : 0);
  if (chunk > B_) chunk = B_;
  if (chunk < 1) chunk = 1;

  // zero the rowsum accumulators (graph-capturable async memset)
  hipMemsetAsync(rs, 0, (size_t)B_ * T_ * sizeof(float), stream);

  // prep: transposed bf16 copies
  transpose_cvt<<<dim3(D_ / 64, T_ / 64, B_), 256, 0, stream>>>(x, xt, T_, D_);
  transpose_cvt<<<dim3(A_ / 64, D_ / 64, 1), 256, 0, stream>>>(W1, W1t, D_, A_);
  transpose_cvt<<<dim3(T_ / 64, A_ / 64, 1), 256, 0, stream>>>(W2, W2t, A_, T_);

  // G1: H^T = W1t @ x^T (M=A,N=T,K=D), transposed write -> H[t][a] bf16, tanh
  gemm_bt<true, true, true, true, false>
      <<<(T_ / 128) * (A_ / 128) * B_, 256, 0, stream>>>(
      W1t, x, H, nullptr, A_, T_, D_, 0, (long)T_ * D_, (long)T_ * A_,
      T_ / 128, A_ / 128);

  for (int b0 = 0; b0 < B_; b0 += chunk) {
    int nb = B_ - b0; if (nb > chunk) nb = chunk;
    // G2: E[s,t] = exp(H @ W2t^T) (transposed write, bf16) + rowsum atomics
    gemm_bt<false, false, true, true, true>
        <<<(T_ / 128) * (T_ / 128) * nb, 256, 0, stream>>>(
        H + (size_t)b0 * T_ * A_, W2t, St, rs + (size_t)b0 * T_,
        T_, T_, A_, (long)T_ * A_, 0, (long)T_ * T_,
        T_ / 128, T_ / 128);
    // G4 (persistent, 3 tiles/block): out[s,d] = (E @ xt^T) / rowsum[s]
    g4_div<<<4 * nb, 512, 0, stream>>>(
        St, xt + (size_t)b0 * (size_t)D_ * T_, rs + (size_t)b0 * T_,
        out + (size_t)b0 * (size_t)T_ * D_);
  }
}

// Round 10
// 322.353 us; speedup vs baseline: 1.0541x; 1.0541x over previous
//
#include <hip/hip_runtime.h>
#include <math.h>

#define B_ 64
#define T_ 1024
#define D_ 768
#define A_ 128

typedef __attribute__((ext_vector_type(4))) float f32x4;
typedef __attribute__((ext_vector_type(8))) short s16x8;
typedef __attribute__((ext_vector_type(4))) short s16x4;

__device__ inline short f2b(float f) {
  union { float f; unsigned u; } v; v.f = f;
  unsigned r = (v.u + 0x7FFFu + ((v.u >> 16) & 1u)) >> 16;
  return (short)r;
}
__device__ inline float b2f(short s) {
  union { unsigned u; float f; } v; v.u = ((unsigned)(unsigned short)s) << 16;
  return v.f;
}

__device__ inline void gll16(const void* g, const void* lds) {
  __builtin_amdgcn_global_load_lds(
      (const __attribute__((address_space(1))) unsigned*)g,
      (__attribute__((address_space(3))) unsigned*)lds, 16, 0, 0);
}

// ---------------------------------------------------------------------------
// G4: 256x256-tile, BK=64, 8-wave, 8-phase counted-vmcnt bf16 GEMM.
// out[s,d] = (sum_t E[s,t]*xt[d,t]) / rowsum[s].  (EXACT R8 version: 12*nb
// grid, batch-major tile order -> L2-tight; R9's persistent 3-tiles/block
// variant REGRESSED: FETCH 134->246MB, +7us — concurrent working set per XCD
// spanned 8 batches' St panels > 4MB L2.)
// T2 st-swizzle (SQ_LDS_BANK_CONFLICT=0, verified R5). 120 VGPR, no spill.
// ---------------------------------------------------------------------------
__global__ __launch_bounds__(512, 2)
void g4_div(const short* __restrict__ Ag, const short* __restrict__ Bg,
            const float* __restrict__ Rs, float* __restrict__ Cg) {
  __shared__ __align__(16) short AS[2][16384];
  __shared__ __align__(16) short BS[2][16384];
  // bijective XCD swizzle
  unsigned nwg = gridDim.x;
  unsigned L = blockIdx.x;
  unsigned xcd = L & 7u, base = L >> 3;
  unsigned q = nwg >> 3, r = nwg & 7u;
  unsigned id = (xcd < r ? xcd * (q + 1) : r * (q + 1) + (xcd - r) * q) + base;
  const int bz = id / 12;
  const int rem = id - bz * 12;
  const int by = rem / 3, bx = rem - (rem / 3) * 3;
  const int m0 = by * 256, n0 = bx * 256;

  const short* Ab = Ag + (size_t)bz * (T_ * T_);
  const short* Bb = Bg + (size_t)bz * (D_ * T_);
  const float* rsb = Rs + (size_t)bz * T_;
  float* Cb = Cg + (size_t)bz * (T_ * D_);

  const int tid = threadIdx.x;
  const int w = tid >> 6, lane = tid & 63;
  const int wr = w >> 2, wc = w & 3;
  const int lr = lane & 15, lq = lane >> 4;
  const int swzk = (lane & 7) ^ ((lane >> 3) & 7);   // source pre-swizzle
  const int abase = (wr * 128 + lr) * 64;
  const int bbase = (wc * 64 + lr) * 64;
  const int sx = lr & 7;
  const int sl0 = (lq ^ sx) * 8;          // kk=0 swizzled slot (shorts)
  const int sl1 = ((4 + lq) ^ sx) * 8;    // kk=1

  f32x4 acc[8][4] = {};
  s16x8 bq[4][2];

#define STG(dst, src, r0, kt)                                                  \
  { _Pragma("unroll")                                                          \
    for (int jj = 0; jj < 2; ++jj) {                                           \
      int rr = jj * 64 + w * 8 + (lane >> 3);                                  \
      gll16((src) + (size_t)((r0) + rr) * 1024 + (kt) + swzk * 8,              \
            (dst) + jj * 4096 + w * 512);                                      \
    } }

#define PHASE(P, Q, VM, STAGE)                                                 \
  {                                                                            \
    s16x8 a0_ = *(const s16x8*)&AS[P][abase + (2 * (Q)) * 1024 + sl0];         \
    s16x8 a1_ = *(const s16x8*)&AS[P][abase + (2 * (Q)) * 1024 + sl1];         \
    s16x8 a2_ = *(const s16x8*)&AS[P][abase + (2 * (Q) + 1) * 1024 + sl0];     \
    s16x8 a3_ = *(const s16x8*)&AS[P][abase + (2 * (Q) + 1) * 1024 + sl1];     \
    if ((Q) == 0) {                                                            \
      _Pragma("unroll")                                                        \
      for (int nf = 0; nf < 4; ++nf) {                                         \
        bq[nf][0] = *(const s16x8*)&BS[P][bbase + nf * 1024 + sl0];            \
        bq[nf][1] = *(const s16x8*)&BS[P][bbase + nf * 1024 + sl1];            \
      }                                                                        \
    }                                                                          \
    STAGE;                                                                     \
    VM;                                                                        \
    __builtin_amdgcn_s_barrier();                                              \
    asm volatile("s_waitcnt lgkmcnt(0)" ::: "memory");                         \
    __builtin_amdgcn_s_setprio(1);                                             \
    _Pragma("unroll")                                                          \
    for (int nf = 0; nf < 4; ++nf) {                                           \
      acc[2*(Q)][nf]   = __builtin_amdgcn_mfma_f32_16x16x32_bf16(a0_, bq[nf][0], acc[2*(Q)][nf], 0, 0, 0);   \
      acc[2*(Q)+1][nf] = __builtin_amdgcn_mfma_f32_16x16x32_bf16(a2_, bq[nf][0], acc[2*(Q)+1][nf], 0, 0, 0); \
    }                                                                          \
    _Pragma("unroll")                                                          \
    for (int nf = 0; nf < 4; ++nf) {                                           \
      acc[2*(Q)][nf]   = __builtin_amdgcn_mfma_f32_16x16x32_bf16(a1_, bq[nf][1], acc[2*(Q)][nf], 0, 0, 0);   \
      acc[2*(Q)+1][nf] = __builtin_amdgcn_mfma_f32_16x16x32_bf16(a3_, bq[nf][1], acc[2*(Q)+1][nf], 0, 0, 0); \
    }                                                                          \
    __builtin_amdgcn_s_setprio(0);                                             \
    __builtin_amdgcn_s_barrier();                                              \
  }

#define VM6 asm volatile("s_waitcnt vmcnt(6)" ::: "memory")
#define VM0 asm volatile("s_waitcnt vmcnt(0)" ::: "memory")
#define NOP (void)0

  // prologue: tile0 (buf0) full + tile1 (buf1) B0,B1,A0
  STG(&BS[0][0],    Bb, n0,       0);
  STG(&BS[0][8192], Bb, n0 + 128, 0);
  STG(&AS[0][0],    Ab, m0,       0);
  STG(&AS[0][8192], Ab, m0 + 128, 0);
  STG(&BS[1][0],    Bb, n0,       64);
  STG(&BS[1][8192], Bb, n0 + 128, 64);
  STG(&AS[1][0],    Ab, m0,       64);
  VM6;                            // 14 issued, drain to 6 -> tile0 landed
  __builtin_amdgcn_s_barrier();

  for (int j = 0; j < 7; ++j) {
    const int kb = j * 128;
    PHASE(0, 0, NOP, STG(&AS[1][8192], Ab, m0 + 128, kb + 64));
    PHASE(0, 1, NOP, STG(&BS[0][0],    Bb, n0,       kb + 128));
    PHASE(0, 2, NOP, STG(&BS[0][8192], Bb, n0 + 128, kb + 128));
    PHASE(0, 3, VM6, STG(&AS[0][0],    Ab, m0,       kb + 128));
    PHASE(1, 0, NOP, STG(&AS[0][8192], Ab, m0 + 128, kb + 128));
    PHASE(1, 1, NOP, STG(&BS[1][0],    Bb, n0,       kb + 192));
    PHASE(1, 2, NOP, STG(&BS[1][8192], Bb, n0 + 128, kb + 192));
    PHASE(1, 3, VM6, STG(&AS[1][0],    Ab, m0,       kb + 192));
  }
  // final iteration: tiles 14 (buf0), 15 (buf1); only t15.A1 left to stage
  PHASE(0, 0, NOP, STG(&AS[1][8192], Ab, m0 + 128, 960));
  PHASE(0, 1, NOP, NOP);
  PHASE(0, 2, NOP, NOP);
  PHASE(0, 3, VM0, NOP);
  PHASE(1, 0, NOP, NOP);
  PHASE(1, 1, NOP, NOP);
  PHASE(1, 2, NOP, NOP);
  PHASE(1, 3, NOP, NOP);

#undef STG
#undef PHASE
#undef VM6
#undef VM0
#undef NOP

  // epilogue: C/D layout col=lane&15, row=(lane>>4)*4+qq; scale by 1/rowsum[s]
#pragma unroll
  for (int mf = 0; mf < 8; ++mf) {
    f32x4 rsv = *(const f32x4*)&rsb[m0 + wr * 128 + mf * 16 + lq * 4];
    f32x4 inv;
#pragma unroll
    for (int qq = 0; qq < 4; ++qq) {
      float iv;
      asm("v_rcp_f32 %0, %1" : "=v"(iv) : "v"(rsv[qq]));
      inv[qq] = iv;
    }
#pragma unroll
    for (int nf = 0; nf < 4; ++nf) {
      int m = m0 + wr * 128 + mf * 16 + lq * 4;
      int n = n0 + wc * 64 + nf * 16 + lr;
#pragma unroll
      for (int qq = 0; qq < 4; ++qq)
        Cb[(size_t)(m + qq) * D_ + n] = acc[mf][nf][qq] * inv[qq];
    }
  }
}

// ---------------------------------------------------------------------------
// bf16 MFMA GEMM (single-buffer 128x128, for G1/G2): C = A @ Bt^T
// WT+OB16 epilogue now goes through an LDS bounce: pack tanh/exp results into
// Es[128][136] (272B rows, 16B-aligned; ~BW-floor banked), barrier, then
// write full 256B contiguous row segments (s16x8, fully coalesced).
// Previous direct path issued 64 distinct 8B stores/wave at 2KB lane stride
// (25% sector utilization on the 128MB St write).
// EXPSUM (G2): also atomically accumulate row-sums of rounded exp into Rs[n].
// ---------------------------------------------------------------------------
template<bool BF32, bool TANH_, bool WT, bool OB16, bool EXPSUM>
__global__ __launch_bounds__(256, 2)
void gemm_bt(const short* __restrict__ Ab, const void* __restrict__ Bv,
             void* __restrict__ Cv, float* __restrict__ Rs,
             int M, int N, int K,
             long sA, long sB, long sC, int gx, int gy) {
  __shared__ __align__(16) short SMEM[128 * 136];  // As|Bs in K-loop; Es overlay in epilogue
  short* As = SMEM;
  short* Bs = SMEM + 128 * 64;
  unsigned nwg = gridDim.x;
  unsigned L = blockIdx.x;
  unsigned xcd = L & 7u, base = L >> 3;
  unsigned q = nwg >> 3, r = nwg & 7u;
  unsigned id = (xcd < r ? xcd * (q + 1) : r * (q + 1) + (xcd - r) * q) + base;
  const int gxy = gx * gy;
  const int bz = id / gxy;
  const int rem = id - bz * gxy;
  const int by = rem / gx;
  const int bx = rem - by * gx;

  const int tid = threadIdx.x;
  const int w = tid >> 6, lane = tid & 63;
  const int n0 = bx * 128, m0 = by * 128;
  const int wr = w >> 1, wc = w & 1;
  const int lr = lane & 15, lq = lane >> 4;
  const short* A = Ab + (size_t)sA * bz;
  const short* Bb16 = nullptr; const float* Bf32 = nullptr;
  if (BF32) Bf32 = (const float*)Bv + (size_t)sB * bz;
  else      Bb16 = (const short*)Bv + (size_t)sB * bz;

  f32x4 acc[4][4] = {};
  const int r8 = lane >> 3, c8 = lane & 7;

  for (int k0 = 0; k0 < K; k0 += 64) {
    __syncthreads();
#pragma unroll
    for (int i = 0; i < 4; ++i) {
      int chunk = w * 4 + i;
      int row = chunk * 8 + r8;
      gll16(A + (size_t)(m0 + row) * K + k0 + c8 * 8, As + chunk * 512);
    }
    if (!BF32) {
#pragma unroll
      for (int i = 0; i < 4; ++i) {
        int chunk = w * 4 + i;
        int row = chunk * 8 + r8;
        gll16(Bb16 + (size_t)(n0 + row) * K + k0 + c8 * 8, Bs + chunk * 512);
      }
    } else {
#pragma unroll
      for (int u = 0; u < 4; ++u) {
        int c = tid * 4 + u;
        int row = c >> 3, k8 = c & 7;
        const float* gp = Bf32 + (size_t)(n0 + row) * K + k0 + k8 * 8;
        float4 f0 = *(const float4*)gp;
        float4 f1 = *(const float4*)(gp + 4);
        s16x8 p;
        p[0] = f2b(f0.x); p[1] = f2b(f0.y); p[2] = f2b(f0.z); p[3] = f2b(f0.w);
        p[4] = f2b(f1.x); p[5] = f2b(f1.y); p[6] = f2b(f1.z); p[7] = f2b(f1.w);
        *(s16x8*)&Bs[row * 64 + k8 * 8] = p;
      }
    }
    __syncthreads();
#pragma unroll
    for (int kk = 0; kk < 2; ++kk) {
      s16x8 a[4], b[4];
#pragma unroll
      for (int mf = 0; mf < 4; ++mf)
        a[mf] = *(const s16x8*)&As[(wr * 64 + mf * 16 + lr) * 64 + kk * 32 + lq * 8];
#pragma unroll
      for (int nf = 0; nf < 4; ++nf)
        b[nf] = *(const s16x8*)&Bs[(wc * 64 + nf * 16 + lr) * 64 + kk * 32 + lq * 8];
#pragma unroll
      for (int mf = 0; mf < 4; ++mf)
#pragma unroll
        for (int nf = 0; nf < 4; ++nf)
          acc[mf][nf] = __builtin_amdgcn_mfma_f32_16x16x32_bf16(
              a[mf], b[nf], acc[mf][nf], 0, 0, 0);
    }
  }

  if (WT && OB16) {
    // ---- LDS-bounce transposed bf16 epilogue ----
    __syncthreads();                       // all waves done reading As/Bs
    float psum[4] = {0.f, 0.f, 0.f, 0.f};
#pragma unroll
    for (int mf = 0; mf < 4; ++mf)
#pragma unroll
      for (int nf = 0; nf < 4; ++nf) {
        int ml = wr * 64 + mf * 16 + lq * 4;      // local m (col of Es row)
        int nl = wc * 64 + nf * 16 + lr;          // local n (Es row)
        s16x4 pk;
#pragma unroll
        for (int qq = 0; qq < 4; ++qq) {
          float v = acc[mf][nf][qq];
          if (TANH_) v = tanhf(v);
          if (EXPSUM) v = __expf(v);
          pk[qq] = f2b(v);
          if (EXPSUM) psum[nf] += b2f(pk[qq]);    // sum the ROUNDED values
        }
        *(s16x4*)&SMEM[nl * 136 + ml] = pk;
      }
    if (EXPSUM) {
      float* rs = Rs + (size_t)T_ * bz;
#pragma unroll
      for (int nf = 0; nf < 4; ++nf) {
        psum[nf] += __shfl_xor(psum[nf], 16);
        psum[nf] += __shfl_xor(psum[nf], 32);
      }
      if (lq == 0) {
#pragma unroll
        for (int nf = 0; nf < 4; ++nf)
          atomicAdd(&rs[n0 + wc * 64 + nf * 16 + lr], psum[nf]);
      }
    }
    __syncthreads();
    // coalesced write: each pass writes 16 rows x 256B contiguous segments
    short* C = (short*)Cv + (size_t)sC * bz;
#pragma unroll
    for (int it = 0; it < 8; ++it) {
      int row = it * 16 + (tid >> 4);             // 0..127 (local n)
      int col = (tid & 15) * 8;                   // 0..120 (local m)
      *(s16x8*)(C + (size_t)(n0 + row) * M + m0 + col) =
          *(const s16x8*)&SMEM[row * 136 + col];
    }
  } else if (WT) {
    float* C = (float*)Cv + (size_t)sC * bz;
#pragma unroll
    for (int mf = 0; mf < 4; ++mf)
#pragma unroll
      for (int nf = 0; nf < 4; ++nf) {
        int mbase = m0 + wr * 64 + mf * 16 + lq * 4;
        int n = n0 + wc * 64 + nf * 16 + lr;
#pragma unroll
        for (int qq = 0; qq < 4; ++qq) {
          float v = acc[mf][nf][qq];
          if (TANH_) v = tanhf(v);
          C[(size_t)n * M + mbase + qq] = v;
        }
      }
  } else {
    float* C = (float*)Cv + (size_t)sC * bz;
#pragma unroll
    for (int mf = 0; mf < 4; ++mf)
#pragma unroll
      for (int nf = 0; nf < 4; ++nf) {
        int m = m0 + wr * 64 + mf * 16 + lq * 4;
        int n = n0 + wc * 64 + nf * 16 + lr;
#pragma unroll
        for (int qq = 0; qq < 4; ++qq) {
          float v = acc[mf][nf][qq];
          if (TANH_) v = tanhf(v);
          C[(size_t)(m + qq) * N + n] = v;
        }
      }
  }
}

// ---------------------------------------------------------------------------
// transpose + fp32->bf16: src [z][R][C] fp32 -> dst [z][C][R] bf16. 64x64 tiles.
// LDS stride 65 + scalar ops: read AND write banks are 2-way max (free).
// ---------------------------------------------------------------------------
__global__ __launch_bounds__(256)
void transpose_cvt(const float* __restrict__ src, short* __restrict__ dst,
                   int R, int C) {
  __shared__ float sh[64][65];
  const int tid = threadIdx.x;
  const float* s = src + (size_t)blockIdx.z * R * C;
  short* d = dst + (size_t)blockIdx.z * R * C;
  const int r0 = blockIdx.y * 64, c0 = blockIdx.x * 64;
#pragma unroll
  for (int u = 0; u < 4; ++u) {
    int e = tid + u * 256;
    int rr = e >> 4, cc4 = (e & 15) * 4;
    float4 v = *(const float4*)&s[(size_t)(r0 + rr) * C + c0 + cc4];
    sh[rr][cc4 + 0] = v.x;
    sh[rr][cc4 + 1] = v.y;
    sh[rr][cc4 + 2] = v.z;
    sh[rr][cc4 + 3] = v.w;
  }
  __syncthreads();
#pragma unroll
  for (int u = 0; u < 4; ++u) {
    int e = tid + u * 256;
    int dr = e >> 4, tc4 = (e & 15) * 4;
    s16x4 pk;
#pragma unroll
    for (int j = 0; j < 4; ++j) pk[j] = f2b(sh[tc4 + j][dr]);
    *(s16x4*)&d[(size_t)(c0 + dr) * R + r0 + tc4] = pk;
  }
}

extern "C" void kernel_launch(void* const* d_in, const int* in_sizes, int n_in,
                              void* d_out, int out_size, void* d_ws, size_t ws_size,
                              hipStream_t stream) {
  const float* x  = (const float*)d_in[0];   // [B,T,D]
  const float* W1 = (const float*)d_in[1];   // [D,A]
  const float* W2 = (const float*)d_in[2];   // [A,T]
  float* out = (float*)d_out;                // [B,T,D] fp32

  // ws (shorts): xt[B,D,T] | W1t[A,D] | W2t[T,A] | H[B,T,A] | rs[B*T fp32] | St[nb,T,T]
  short* xt  = (short*)d_ws;
  short* W1t = xt + (size_t)B_ * D_ * T_;
  short* W2t = W1t + (size_t)A_ * D_;
  short* H   = W2t + (size_t)T_ * A_;
  float* rs  = (float*)(H + (size_t)B_ * T_ * A_);
  short* St  = (short*)(rs + (size_t)B_ * T_);
  size_t fixed_bytes = (size_t)((char*)St - (char*)xt);
  long avail = (long)ws_size - (long)fixed_bytes;
  long per_b = (long)T_ * T_ * sizeof(short);
  int chunk = (int)(avail > 0 ? avail / per_b : 0);
  if (chunk > B_) chunk = B_;
  if (chunk < 1) chunk = 1;

  // zero the rowsum accumulators (graph-capturable async memset)
  hipMemsetAsync(rs, 0, (size_t)B_ * T_ * sizeof(float), stream);

  // prep: transposed bf16 copies
  transpose_cvt<<<dim3(D_ / 64, T_ / 64, B_), 256, 0, stream>>>(x, xt, T_, D_);
  transpose_cvt<<<dim3(A_ / 64, D_ / 64, 1), 256, 0, stream>>>(W1, W1t, D_, A_);
  transpose_cvt<<<dim3(T_ / 64, A_ / 64, 1), 256, 0, stream>>>(W2, W2t, A_, T_);

  // G1: H^T = W1t @ x^T (M=A,N=T,K=D), transposed write -> H[t][a] bf16, tanh
  gemm_bt<true, true, true, true, false>
      <<<(T_ / 128) * (A_ / 128) * B_, 256, 0, stream>>>(
      W1t, x, H, nullptr, A_, T_, D_, 0, (long)T_ * D_, (long)T_ * A_,
      T_ / 128, A_ / 128);

  for (int b0 = 0; b0 < B_; b0 += chunk) {
    int nb = B_ - b0; if (nb > chunk) nb = chunk;
    // G2: E[s,t] = exp(H @ W2t^T) (transposed write, bf16) + rowsum atomics
    gemm_bt<false, false, true, true, true>
        <<<(T_ / 128) * (T_ / 128) * nb, 256, 0, stream>>>(
        H + (size_t)b0 * T_ * A_, W2t, St, rs + (size_t)b0 * T_,
        T_, T_, A_, (long)T_ * A_, 0, (long)T_ * T_,
        T_ / 128, T_ / 128);
    // G4: out[s,d] = (E @ xt^T) / rowsum[s]
    g4_div<<<12 * nb, 512, 0, stream>>>(
        St, xt + (size_t)b0 * (size_t)D_ * T_, rs + (size_t)b0 * T_,
        out + (size_t)b0 * (size_t)T_ * D_);
  }
}

// Round 11
// 293.050 us; speedup vs baseline: 1.1595x; 1.1000x over previous
//
#include <hip/hip_runtime.h>
#include <math.h>

#define B_ 64
#define T_ 1024
#define D_ 768
#define A_ 128

typedef __attribute__((ext_vector_type(4))) float f32x4;
typedef __attribute__((ext_vector_type(8))) short s16x8;
typedef __attribute__((ext_vector_type(4))) short s16x4;

__device__ inline short f2b(float f) {
  union { float f; unsigned u; } v; v.f = f;
  unsigned r = (v.u + 0x7FFFu + ((v.u >> 16) & 1u)) >> 16;
  return (short)r;
}
__device__ inline float b2f(short s) {
  union { unsigned u; float f; } v; v.u = ((unsigned)(unsigned short)s) << 16;
  return v.f;
}

__device__ inline void gll16(const void* g, const void* lds) {
  __builtin_amdgcn_global_load_lds(
      (const __attribute__((address_space(1))) unsigned*)g,
      (__attribute__((address_space(3))) unsigned*)lds, 16, 0, 0);
}

// ---------------------------------------------------------------------------
// G4: 256x256-tile, BK=64, 8-wave, 8-phase counted-vmcnt bf16 GEMM (R8/R10
// version — best measured: 137us, FETCH 134MB, SQ_LDS_BANK_CONFLICT=0).
// out[s,d] = (sum_t E[s,t]*xt[d,t]) / rowsum[s].
// ---------------------------------------------------------------------------
__global__ __launch_bounds__(512, 2)
void g4_div(const short* __restrict__ Ag, const short* __restrict__ Bg,
            const float* __restrict__ Rs, float* __restrict__ Cg) {
  __shared__ __align__(16) short AS[2][16384];
  __shared__ __align__(16) short BS[2][16384];
  // bijective XCD swizzle
  unsigned nwg = gridDim.x;
  unsigned L = blockIdx.x;
  unsigned xcd = L & 7u, base = L >> 3;
  unsigned q = nwg >> 3, r = nwg & 7u;
  unsigned id = (xcd < r ? xcd * (q + 1) : r * (q + 1) + (xcd - r) * q) + base;
  const int bz = id / 12;
  const int rem = id - bz * 12;
  const int by = rem / 3, bx = rem - (rem / 3) * 3;
  const int m0 = by * 256, n0 = bx * 256;

  const short* Ab = Ag + (size_t)bz * (T_ * T_);
  const short* Bb = Bg + (size_t)bz * (D_ * T_);
  const float* rsb = Rs + (size_t)bz * T_;
  float* Cb = Cg + (size_t)bz * (T_ * D_);

  const int tid = threadIdx.x;
  const int w = tid >> 6, lane = tid & 63;
  const int wr = w >> 2, wc = w & 3;
  const int lr = lane & 15, lq = lane >> 4;
  const int swzk = (lane & 7) ^ ((lane >> 3) & 7);   // source pre-swizzle
  const int abase = (wr * 128 + lr) * 64;
  const int bbase = (wc * 64 + lr) * 64;
  const int sx = lr & 7;
  const int sl0 = (lq ^ sx) * 8;          // kk=0 swizzled slot (shorts)
  const int sl1 = ((4 + lq) ^ sx) * 8;    // kk=1

  f32x4 acc[8][4] = {};
  s16x8 bq[4][2];

#define STG(dst, src, r0, kt)                                                  \
  { _Pragma("unroll")                                                          \
    for (int jj = 0; jj < 2; ++jj) {                                           \
      int rr = jj * 64 + w * 8 + (lane >> 3);                                  \
      gll16((src) + (size_t)((r0) + rr) * 1024 + (kt) + swzk * 8,              \
            (dst) + jj * 4096 + w * 512);                                      \
    } }

#define PHASE(P, Q, VM, STAGE)                                                 \
  {                                                                            \
    s16x8 a0_ = *(const s16x8*)&AS[P][abase + (2 * (Q)) * 1024 + sl0];         \
    s16x8 a1_ = *(const s16x8*)&AS[P][abase + (2 * (Q)) * 1024 + sl1];         \
    s16x8 a2_ = *(const s16x8*)&AS[P][abase + (2 * (Q) + 1) * 1024 + sl0];     \
    s16x8 a3_ = *(const s16x8*)&AS[P][abase + (2 * (Q) + 1) * 1024 + sl1];     \
    if ((Q) == 0) {                                                            \
      _Pragma("unroll")                                                        \
      for (int nf = 0; nf < 4; ++nf) {                                         \
        bq[nf][0] = *(const s16x8*)&BS[P][bbase + nf * 1024 + sl0];            \
        bq[nf][1] = *(const s16x8*)&BS[P][bbase + nf * 1024 + sl1];            \
      }                                                                        \
    }                                                                          \
    STAGE;                                                                     \
    VM;                                                                        \
    __builtin_amdgcn_s_barrier();                                              \
    asm volatile("s_waitcnt lgkmcnt(0)" ::: "memory");                         \
    __builtin_amdgcn_s_setprio(1);                                             \
    _Pragma("unroll")                                                          \
    for (int nf = 0; nf < 4; ++nf) {                                           \
      acc[2*(Q)][nf]   = __builtin_amdgcn_mfma_f32_16x16x32_bf16(a0_, bq[nf][0], acc[2*(Q)][nf], 0, 0, 0);   \
      acc[2*(Q)+1][nf] = __builtin_amdgcn_mfma_f32_16x16x32_bf16(a2_, bq[nf][0], acc[2*(Q)+1][nf], 0, 0, 0); \
    }                                                                          \
    _Pragma("unroll")                                                          \
    for (int nf = 0; nf < 4; ++nf) {                                           \
      acc[2*(Q)][nf]   = __builtin_amdgcn_mfma_f32_16x16x32_bf16(a1_, bq[nf][1], acc[2*(Q)][nf], 0, 0, 0);   \
      acc[2*(Q)+1][nf] = __builtin_amdgcn_mfma_f32_16x16x32_bf16(a3_, bq[nf][1], acc[2*(Q)+1][nf], 0, 0, 0); \
    }                                                                          \
    __builtin_amdgcn_s_setprio(0);                                             \
    __builtin_amdgcn_s_barrier();                                              \
  }

#define VM6 asm volatile("s_waitcnt vmcnt(6)" ::: "memory")
#define VM0 asm volatile("s_waitcnt vmcnt(0)" ::: "memory")
#define NOP (void)0

  // prologue: tile0 (buf0) full + tile1 (buf1) B0,B1,A0
  STG(&BS[0][0],    Bb, n0,       0);
  STG(&BS[0][8192], Bb, n0 + 128, 0);
  STG(&AS[0][0],    Ab, m0,       0);
  STG(&AS[0][8192], Ab, m0 + 128, 0);
  STG(&BS[1][0],    Bb, n0,       64);
  STG(&BS[1][8192], Bb, n0 + 128, 64);
  STG(&AS[1][0],    Ab, m0,       64);
  VM6;                            // 14 issued, drain to 6 -> tile0 landed
  __builtin_amdgcn_s_barrier();

  for (int j = 0; j < 7; ++j) {
    const int kb = j * 128;
    PHASE(0, 0, NOP, STG(&AS[1][8192], Ab, m0 + 128, kb + 64));
    PHASE(0, 1, NOP, STG(&BS[0][0],    Bb, n0,       kb + 128));
    PHASE(0, 2, NOP, STG(&BS[0][8192], Bb, n0 + 128, kb + 128));
    PHASE(0, 3, VM6, STG(&AS[0][0],    Ab, m0,       kb + 128));
    PHASE(1, 0, NOP, STG(&AS[0][8192], Ab, m0 + 128, kb + 128));
    PHASE(1, 1, NOP, STG(&BS[1][0],    Bb, n0,       kb + 192));
    PHASE(1, 2, NOP, STG(&BS[1][8192], Bb, n0 + 128, kb + 192));
    PHASE(1, 3, VM6, STG(&AS[1][0],    Ab, m0,       kb + 192));
  }
  // final iteration: tiles 14 (buf0), 15 (buf1); only t15.A1 left to stage
  PHASE(0, 0, NOP, STG(&AS[1][8192], Ab, m0 + 128, 960));
  PHASE(0, 1, NOP, NOP);
  PHASE(0, 2, NOP, NOP);
  PHASE(0, 3, VM0, NOP);
  PHASE(1, 0, NOP, NOP);
  PHASE(1, 1, NOP, NOP);
  PHASE(1, 2, NOP, NOP);
  PHASE(1, 3, NOP, NOP);

#undef STG
#undef PHASE
#undef VM6
#undef VM0
#undef NOP

  // epilogue: C/D layout col=lane&15, row=(lane>>4)*4+qq; scale by 1/rowsum[s]
#pragma unroll
  for (int mf = 0; mf < 8; ++mf) {
    f32x4 rsv = *(const f32x4*)&rsb[m0 + wr * 128 + mf * 16 + lq * 4];
    f32x4 inv;
#pragma unroll
    for (int qq = 0; qq < 4; ++qq) {
      float iv;
      asm("v_rcp_f32 %0, %1" : "=v"(iv) : "v"(rsv[qq]));
      inv[qq] = iv;
    }
#pragma unroll
    for (int nf = 0; nf < 4; ++nf) {
      int m = m0 + wr * 128 + mf * 16 + lq * 4;
      int n = n0 + wc * 64 + nf * 16 + lr;
#pragma unroll
      for (int qq = 0; qq < 4; ++qq)
        Cb[(size_t)(m + qq) * D_ + n] = acc[mf][nf][qq] * inv[qq];
    }
  }
}

// ---------------------------------------------------------------------------
// bf16 MFMA GEMM (128x128 tile, templated K-step BK) for G1/G2.
//   BK=64  (G1, K=768, 12 steps) / BK=128 (G2, K=128 -> SINGLE step: one
//   stage+sync round instead of two; K=128 loop was latency/sync-bound).
// WT+OB16 epilogue: LDS-bounce to coalesced 256B row writes (R10, +18us win).
// EXPSUM (G2): atomic rowsums of rounded exp into Rs[n].
// XT (G1): ALSO emit xt[d][t] bf16. G1 reads all of x as its fp32 B-operand;
// per K-step the converted bf16 frags (parr) are bounced through padded
// Ts[64][136] (transpose in LDS) and written as coalesced 256B t-segments.
// This deletes the dedicated x transpose pass (288MB ≈ 46us at BW floor).
// ---------------------------------------------------------------------------
template<int BK, bool BF32, bool TANH_, bool WT, bool OB16, bool EXPSUM, bool XT>
__global__ __launch_bounds__(256, 2)
void gemm_bt(const short* __restrict__ Ab, const void* __restrict__ Bv,
             void* __restrict__ Cv, float* __restrict__ Rs,
             short* __restrict__ Xt,
             int M, int N, int K,
             long sA, long sB, long sC, int gx, int gy) {
  constexpr int OPS = 128 * BK;                 // shorts per operand tile
  constexpr int BOUNCE = 128 * 136;             // epilogue bounce shorts
  constexpr int BASE = (2 * OPS > BOUNCE ? 2 * OPS : BOUNCE);
  __shared__ __align__(16) short SMEM[BASE + (XT ? 64 * 136 : 0)];
  short* As = SMEM;
  short* Bs = SMEM + OPS;
  short* Ts = SMEM + 2 * OPS;                   // XT only; disjoint from As/Bs

  unsigned nwg = gridDim.x;
  unsigned L = blockIdx.x;
  unsigned xcd = L & 7u, base = L >> 3;
  unsigned q = nwg >> 3, r = nwg & 7u;
  unsigned id = (xcd < r ? xcd * (q + 1) : r * (q + 1) + (xcd - r) * q) + base;
  const int gxy = gx * gy;
  const int bz = id / gxy;
  const int rem = id - bz * gxy;
  const int by = rem / gx;
  const int bx = rem - by * gx;

  const int tid = threadIdx.x;
  const int w = tid >> 6, lane = tid & 63;
  const int n0 = bx * 128, m0 = by * 128;
  const int wr = w >> 1, wc = w & 1;
  const int lr = lane & 15, lq = lane >> 4;
  const short* A = Ab + (size_t)sA * bz;
  const short* Bb16 = nullptr; const float* Bf32 = nullptr;
  if (BF32) Bf32 = (const float*)Bv + (size_t)sB * bz;
  else      Bb16 = (const short*)Bv + (size_t)sB * bz;
  short* Xtb = XT ? Xt + (size_t)bz * ((size_t)D_ * T_) : nullptr;

  f32x4 acc[4][4] = {};

  // gll16 staging geometry: 1KB chunk = 64 lanes x 16B
  constexpr int LPR = BK / 8;      // lanes per row
  constexpr int RPC = 64 / LPR;    // rows per chunk
  constexpr int CPT = BK / 16;     // chunks per wave per operand
  const int rl = lane / LPR;
  const int cl = (lane % LPR) * 8;

  for (int k0 = 0; k0 < K; k0 += BK) {
    __syncthreads();
#pragma unroll
    for (int i = 0; i < CPT; ++i) {
      int chunk = w * CPT + i;
      int row = chunk * RPC + rl;
      gll16(A + (size_t)(m0 + row) * K + k0 + cl, As + chunk * 512);
    }
    s16x8 parr[4];
    if (!BF32) {
#pragma unroll
      for (int i = 0; i < CPT; ++i) {
        int chunk = w * CPT + i;
        int row = chunk * RPC + rl;
        gll16(Bb16 + (size_t)(n0 + row) * K + k0 + cl, Bs + chunk * 512);
      }
    } else {
      // BK==64 reg-staged fp32->bf16 convert path
#pragma unroll
      for (int u = 0; u < 4; ++u) {
        int c = tid * 4 + u;
        int row = c >> 3, k8 = c & 7;
        const float* gp = Bf32 + (size_t)(n0 + row) * K + k0 + k8 * 8;
        float4 f0 = *(const float4*)gp;
        float4 f1 = *(const float4*)(gp + 4);
        s16x8 p;
        p[0] = f2b(f0.x); p[1] = f2b(f0.y); p[2] = f2b(f0.z); p[3] = f2b(f0.w);
        p[4] = f2b(f1.x); p[5] = f2b(f1.y); p[6] = f2b(f1.z); p[7] = f2b(f1.w);
        parr[u] = p;
        *(s16x8*)&Bs[row * 64 + k8 * 8] = p;
      }
    }
    __syncthreads();
#pragma unroll
    for (int kk = 0; kk < BK / 32; ++kk) {
      s16x8 a[4], b[4];
#pragma unroll
      for (int mf = 0; mf < 4; ++mf)
        a[mf] = *(const s16x8*)&As[(wr * 64 + mf * 16 + lr) * BK + kk * 32 + lq * 8];
#pragma unroll
      for (int nf = 0; nf < 4; ++nf)
        b[nf] = *(const s16x8*)&Bs[(wc * 64 + nf * 16 + lr) * BK + kk * 32 + lq * 8];
#pragma unroll
      for (int mf = 0; mf < 4; ++mf)
#pragma unroll
        for (int nf = 0; nf < 4; ++nf)
          acc[mf][nf] = __builtin_amdgcn_mfma_f32_16x16x32_bf16(
              a[mf], b[nf], acc[mf][nf], 0, 0, 0);
    }
    if constexpr (XT) {
      // transpose bounce: parr (x bf16, [t-local row][d-local k8*8+j]) -> Ts[d][t]
#pragma unroll
      for (int u = 0; u < 4; ++u) {
        int c = tid * 4 + u;
        int row = c >> 3, k8 = c & 7;
#pragma unroll
        for (int j = 0; j < 8; ++j) Ts[(k8 * 8 + j) * 136 + row] = parr[u][j];
      }
      __syncthreads();
      // coalesced xt write: 16 lanes cover one d-row's 128 t (256B)
#pragma unroll
      for (int u = 0; u < 4; ++u) {
        int task = tid + u * 256;          // 0..1023 = 64 d x 16 t8
        int dd = task >> 4, t8 = task & 15;
        *(s16x8*)&Xtb[(size_t)(k0 + dd) * T_ + n0 + t8 * 8] =
            *(const s16x8*)&Ts[dd * 136 + t8 * 8];
      }
    }
  }

  if (WT && OB16) {
    // ---- LDS-bounce transposed bf16 epilogue ----
    __syncthreads();                       // all waves done with As/Bs/Ts
    float psum[4] = {0.f, 0.f, 0.f, 0.f};
#pragma unroll
    for (int mf = 0; mf < 4; ++mf)
#pragma unroll
      for (int nf = 0; nf < 4; ++nf) {
        int ml = wr * 64 + mf * 16 + lq * 4;      // local m (col of row)
        int nl = wc * 64 + nf * 16 + lr;          // local n (row)
        s16x4 pk;
#pragma unroll
        for (int qq = 0; qq < 4; ++qq) {
          float v = acc[mf][nf][qq];
          if (TANH_) v = tanhf(v);
          if (EXPSUM) v = __expf(v);
          pk[qq] = f2b(v);
          if (EXPSUM) psum[nf] += b2f(pk[qq]);    // sum the ROUNDED values
        }
        *(s16x4*)&SMEM[nl * 136 + ml] = pk;
      }
    if (EXPSUM) {
      float* rs = Rs + (size_t)T_ * bz;
#pragma unroll
      for (int nf = 0; nf < 4; ++nf) {
        psum[nf] += __shfl_xor(psum[nf], 16);
        psum[nf] += __shfl_xor(psum[nf], 32);
      }
      if (lq == 0) {
#pragma unroll
        for (int nf = 0; nf < 4; ++nf)
          atomicAdd(&rs[n0 + wc * 64 + nf * 16 + lr], psum[nf]);
      }
    }
    __syncthreads();
    short* C = (short*)Cv + (size_t)sC * bz;
#pragma unroll
    for (int it = 0; it < 8; ++it) {
      int row = it * 16 + (tid >> 4);             // 0..127 (local n)
      int col = (tid & 15) * 8;                   // 0..120 (local m)
      *(s16x8*)(C + (size_t)(n0 + row) * M + m0 + col) =
          *(const s16x8*)&SMEM[row * 136 + col];
    }
  } else if (WT) {
    float* C = (float*)Cv + (size_t)sC * bz;
#pragma unroll
    for (int mf = 0; mf < 4; ++mf)
#pragma unroll
      for (int nf = 0; nf < 4; ++nf) {
        int mbase = m0 + wr * 64 + mf * 16 + lq * 4;
        int n = n0 + wc * 64 + nf * 16 + lr;
#pragma unroll
        for (int qq = 0; qq < 4; ++qq) {
          float v = acc[mf][nf][qq];
          if (TANH_) v = tanhf(v);
          C[(size_t)n * M + mbase + qq] = v;
        }
      }
  } else {
    float* C = (float*)Cv + (size_t)sC * bz;
#pragma unroll
    for (int mf = 0; mf < 4; ++mf)
#pragma unroll
      for (int nf = 0; nf < 4; ++nf) {
        int m = m0 + wr * 64 + mf * 16 + lq * 4;
        int n = n0 + wc * 64 + nf * 16 + lr;
#pragma unroll
        for (int qq = 0; qq < 4; ++qq) {
          float v = acc[mf][nf][qq];
          if (TANH_) v = tanhf(v);
          C[(size_t)(m + qq) * N + n] = v;
        }
      }
  }
}

// ---------------------------------------------------------------------------
// transpose + fp32->bf16 (W1/W2 only now; x handled inside G1 via XT).
// ---------------------------------------------------------------------------
__global__ __launch_bounds__(256)
void transpose_cvt(const float* __restrict__ src, short* __restrict__ dst,
                   int R, int C) {
  __shared__ float sh[64][65];
  const int tid = threadIdx.x;
  const float* s = src + (size_t)blockIdx.z * R * C;
  short* d = dst + (size_t)blockIdx.z * R * C;
  const int r0 = blockIdx.y * 64, c0 = blockIdx.x * 64;
#pragma unroll
  for (int u = 0; u < 4; ++u) {
    int e = tid + u * 256;
    int rr = e >> 4, cc4 = (e & 15) * 4;
    float4 v = *(const float4*)&s[(size_t)(r0 + rr) * C + c0 + cc4];
    sh[rr][cc4 + 0] = v.x;
    sh[rr][cc4 + 1] = v.y;
    sh[rr][cc4 + 2] = v.z;
    sh[rr][cc4 + 3] = v.w;
  }
  __syncthreads();
#pragma unroll
  for (int u = 0; u < 4; ++u) {
    int e = tid + u * 256;
    int dr = e >> 4, tc4 = (e & 15) * 4;
    s16x4 pk;
#pragma unroll
    for (int j = 0; j < 4; ++j) pk[j] = f2b(sh[tc4 + j][dr]);
    *(s16x4*)&d[(size_t)(c0 + dr) * R + r0 + tc4] = pk;
  }
}

extern "C" void kernel_launch(void* const* d_in, const int* in_sizes, int n_in,
                              void* d_out, int out_size, void* d_ws, size_t ws_size,
                              hipStream_t stream) {
  const float* x  = (const float*)d_in[0];   // [B,T,D]
  const float* W1 = (const float*)d_in[1];   // [D,A]
  const float* W2 = (const float*)d_in[2];   // [A,T]
  float* out = (float*)d_out;                // [B,T,D] fp32

  // ws (shorts): xt[B,D,T] | W1t[A,D] | W2t[T,A] | H[B,T,A] | rs[B*T fp32] | St[nb,T,T]
  short* xt  = (short*)d_ws;
  short* W1t = xt + (size_t)B_ * D_ * T_;
  short* W2t = W1t + (size_t)A_ * D_;
  short* H   = W2t + (size_t)T_ * A_;
  float* rs  = (float*)(H + (size_t)B_ * T_ * A_);
  short* St  = (short*)(rs + (size_t)B_ * T_);
  size_t fixed_bytes = (size_t)((char*)St - (char*)xt);
  long avail = (long)ws_size - (long)fixed_bytes;
  long per_b = (long)T_ * T_ * sizeof(short);
  int chunk = (int)(avail > 0 ? avail / per_b : 0);
  if (chunk > B_) chunk = B_;
  if (chunk < 1) chunk = 1;

  // zero the rowsum accumulators (graph-capturable async memset)
  hipMemsetAsync(rs, 0, (size_t)B_ * T_ * sizeof(float), stream);

  // prep: transposed bf16 copies of the small weights only
  transpose_cvt<<<dim3(A_ / 64, D_ / 64, 1), 256, 0, stream>>>(W1, W1t, D_, A_);
  transpose_cvt<<<dim3(T_ / 64, A_ / 64, 1), 256, 0, stream>>>(W2, W2t, A_, T_);

  // G1: H^T = W1t @ x^T (M=A,N=T,K=D), tanh, transposed bf16 write -> H[t][a];
  //     ALSO emits xt[d][t] bf16 (XT path) from its x reg-staging.
  gemm_bt<64, true, true, true, true, false, true>
      <<<(T_ / 128) * (A_ / 128) * B_, 256, 0, stream>>>(
      W1t, x, H, nullptr, xt, A_, T_, D_, 0, (long)T_ * D_, (long)T_ * A_,
      T_ / 128, A_ / 128);

  for (int b0 = 0; b0 < B_; b0 += chunk) {
    int nb = B_ - b0; if (nb > chunk) nb = chunk;
    // G2: E[s,t] = exp(H @ W2t^T), single K=128 step, transposed bf16 write
    //     + rowsum atomics
    gemm_bt<128, false, false, true, true, true, false>
        <<<(T_ / 128) * (T_ / 128) * nb, 256, 0, stream>>>(
        H + (size_t)b0 * T_ * A_, W2t, St, rs + (size_t)b0 * T_, nullptr,
        T_, T_, A_, (long)T_ * A_, 0, (long)T_ * T_,
        T_ / 128, T_ / 128);
    // G4: out[s,d] = (E @ xt^T) / rowsum[s]
    g4_div<<<12 * nb, 512, 0, stream>>>(
        St, xt + (size_t)b0 * (size_t)D_ * T_, rs + (size_t)b0 * T_,
        out + (size_t)b0 * (size_t)T_ * D_);
  }
}

// Round 13
// 285.267 us; speedup vs baseline: 1.1911x; 1.0273x over previous
//
#include <hip/hip_runtime.h>
#include <math.h>

#define B_ 64
#define T_ 1024
#define D_ 768
#define A_ 128

typedef __attribute__((ext_vector_type(4))) float f32x4;
typedef __attribute__((ext_vector_type(8))) short s16x8;
typedef __attribute__((ext_vector_type(4))) short s16x4;

__device__ inline short f2b(float f) {
  union { float f; unsigned u; } v; v.f = f;
  unsigned r = (v.u + 0x7FFFu + ((v.u >> 16) & 1u)) >> 16;
  return (short)r;
}
__device__ inline float b2f(short s) {
  union { unsigned u; float f; } v; v.u = ((unsigned)(unsigned short)s) << 16;
  return v.f;
}

__device__ inline void gll16(const void* g, const void* lds) {
  __builtin_amdgcn_global_load_lds(
      (const __attribute__((address_space(1))) unsigned*)g,
      (__attribute__((address_space(3))) unsigned*)lds, 16, 0, 0);
}

// ---------------------------------------------------------------------------
// G4: 256x256-tile, BK=64, 8-wave, FUSED 4-phase (32 MFMA/phase) counted-vmcnt
// bf16 GEMM.  out[s,d] = (sum_t E[s,t]*xt[d,t]) / rowsum[s].
// SCHEDULE INVARIANT (R12 lesson): a buffer region is only STG'd in a phase
// AFTER the phase whose ds_reads touch it — that phase's lgkmcnt(0) + end
// barrier force the reads complete before the write is issued. R12 violated
// this (B-halves staged in their own bq-read phase) -> intermittent 4.5e-2.
// Staging (kb=j*128; 4 vm-units/phase; steady-state leftover = 4 units):
//   ph1 {A1h1,A1h2 @kb+64}            (AS[1] last read prev ph4)
//   ph2 {B0h1,B0h2 @kb+128} + VM4     (BS[0] bq read in ph1; VM4 retires
//                                      {B1',A1} -> buf1 landed before ph3)
//   ph3 {A0h1,A0h2 @kb+128}           (AS[0] last read ph2-mid)
//   ph4 {B1h1,B1h2 @kb+192} + VM4     (BS[1] bq read in ph3; VM4 retires
//                                      {B0,A0} -> buf0 landed before next ph1)
// Mid-phase Q+2/Q+3 ds_reads overlap the first MFMA clusters; barriers halved
// vs the R11 8-phase (which ran ~1580cy/phase vs ~530cy work).
// T2 st-swizzle (SQ_LDS_BANK_CONFLICT=0 verified R5).
// ---------------------------------------------------------------------------
__global__ __launch_bounds__(512, 2)
void g4_div(const short* __restrict__ Ag, const short* __restrict__ Bg,
            const float* __restrict__ Rs, float* __restrict__ Cg) {
  __shared__ __align__(16) short AS[2][16384];
  __shared__ __align__(16) short BS[2][16384];
  // bijective XCD swizzle
  unsigned nwg = gridDim.x;
  unsigned L = blockIdx.x;
  unsigned xcd = L & 7u, base = L >> 3;
  unsigned q = nwg >> 3, r = nwg & 7u;
  unsigned id = (xcd < r ? xcd * (q + 1) : r * (q + 1) + (xcd - r) * q) + base;
  const int bz = id / 12;
  const int rem = id - bz * 12;
  const int by = rem / 3, bx = rem - (rem / 3) * 3;
  const int m0 = by * 256, n0 = bx * 256;

  const short* Ab = Ag + (size_t)bz * (T_ * T_);
  const short* Bb = Bg + (size_t)bz * (D_ * T_);
  const float* rsb = Rs + (size_t)bz * T_;
  float* Cb = Cg + (size_t)bz * (T_ * D_);

  const int tid = threadIdx.x;
  const int w = tid >> 6, lane = tid & 63;
  const int wr = w >> 2, wc = w & 3;
  const int lr = lane & 15, lq = lane >> 4;
  const int swzk = (lane & 7) ^ ((lane >> 3) & 7);   // source pre-swizzle
  const int abase = (wr * 128 + lr) * 64;
  const int bbase = (wc * 64 + lr) * 64;
  const int sx = lr & 7;
  const int sl0 = (lq ^ sx) * 8;          // kk=0 swizzled slot (shorts)
  const int sl1 = ((4 + lq) ^ sx) * 8;    // kk=1

  f32x4 acc[8][4] = {};
  s16x8 bq[4][2];

#define STG(dst, src, r0, kt)                                                  \
  { _Pragma("unroll")                                                          \
    for (int jj = 0; jj < 2; ++jj) {                                           \
      int rr = jj * 64 + w * 8 + (lane >> 3);                                  \
      gll16((src) + (size_t)((r0) + rr) * 1024 + (kt) + swzk * 8,              \
            (dst) + jj * 4096 + w * 512);                                      \
    } }

// fused phase: quadrants Q0,Q0+1 read at top; Q0+2,Q0+3 read mid-phase,
// overlapping the first MFMA clusters. No STG in this phase targets a region
// read in this phase (see invariant above).
#define PH2(P, Q0, VM, ...)                                                    \
  {                                                                            \
    s16x8 a0_ = *(const s16x8*)&AS[P][abase + (2 * (Q0)) * 1024 + sl0];        \
    s16x8 a1_ = *(const s16x8*)&AS[P][abase + (2 * (Q0)) * 1024 + sl1];        \
    s16x8 a2_ = *(const s16x8*)&AS[P][abase + (2 * (Q0) + 1) * 1024 + sl0];    \
    s16x8 a3_ = *(const s16x8*)&AS[P][abase + (2 * (Q0) + 1) * 1024 + sl1];    \
    if ((Q0) == 0) {                                                           \
      _Pragma("unroll")                                                        \
      for (int nf = 0; nf < 4; ++nf) {                                         \
        bq[nf][0] = *(const s16x8*)&BS[P][bbase + nf * 1024 + sl0];            \
        bq[nf][1] = *(const s16x8*)&BS[P][bbase + nf * 1024 + sl1];            \
      }                                                                        \
    }                                                                          \
    __VA_ARGS__;                                                               \
    VM;                                                                        \
    __builtin_amdgcn_s_barrier();                                              \
    asm volatile("s_waitcnt lgkmcnt(0)" ::: "memory");                         \
    __builtin_amdgcn_s_setprio(1);                                             \
    _Pragma("unroll")                                                          \
    for (int nf = 0; nf < 4; ++nf) {                                           \
      acc[2*(Q0)][nf]   = __builtin_amdgcn_mfma_f32_16x16x32_bf16(a0_, bq[nf][0], acc[2*(Q0)][nf], 0, 0, 0);   \
      acc[2*(Q0)+1][nf] = __builtin_amdgcn_mfma_f32_16x16x32_bf16(a2_, bq[nf][0], acc[2*(Q0)+1][nf], 0, 0, 0); \
    }                                                                          \
    s16x8 a4_ = *(const s16x8*)&AS[P][abase + (2 * (Q0) + 2) * 1024 + sl0];    \
    s16x8 a5_ = *(const s16x8*)&AS[P][abase + (2 * (Q0) + 2) * 1024 + sl1];    \
    s16x8 a6_ = *(const s16x8*)&AS[P][abase + (2 * (Q0) + 3) * 1024 + sl0];    \
    s16x8 a7_ = *(const s16x8*)&AS[P][abase + (2 * (Q0) + 3) * 1024 + sl1];    \
    _Pragma("unroll")                                                          \
    for (int nf = 0; nf < 4; ++nf) {                                           \
      acc[2*(Q0)][nf]   = __builtin_amdgcn_mfma_f32_16x16x32_bf16(a1_, bq[nf][1], acc[2*(Q0)][nf], 0, 0, 0);   \
      acc[2*(Q0)+1][nf] = __builtin_amdgcn_mfma_f32_16x16x32_bf16(a3_, bq[nf][1], acc[2*(Q0)+1][nf], 0, 0, 0); \
    }                                                                          \
    _Pragma("unroll")                                                          \
    for (int nf = 0; nf < 4; ++nf) {                                           \
      acc[2*(Q0)+2][nf] = __builtin_amdgcn_mfma_f32_16x16x32_bf16(a4_, bq[nf][0], acc[2*(Q0)+2][nf], 0, 0, 0); \
      acc[2*(Q0)+3][nf] = __builtin_amdgcn_mfma_f32_16x16x32_bf16(a6_, bq[nf][0], acc[2*(Q0)+3][nf], 0, 0, 0); \
    }                                                                          \
    _Pragma("unroll")                                                          \
    for (int nf = 0; nf < 4; ++nf) {                                           \
      acc[2*(Q0)+2][nf] = __builtin_amdgcn_mfma_f32_16x16x32_bf16(a5_, bq[nf][1], acc[2*(Q0)+2][nf], 0, 0, 0); \
      acc[2*(Q0)+3][nf] = __builtin_amdgcn_mfma_f32_16x16x32_bf16(a7_, bq[nf][1], acc[2*(Q0)+3][nf], 0, 0, 0); \
    }                                                                          \
    __builtin_amdgcn_s_setprio(0);                                             \
    __builtin_amdgcn_s_barrier();                                              \
  }

#define VM4 asm volatile("s_waitcnt vmcnt(4)" ::: "memory")
#define VM0 asm volatile("s_waitcnt vmcnt(0)" ::: "memory")
#define NOP (void)0

  // prologue: buf0 (tile@0) full + buf1 (tile@64) B halves
  STG(&BS[0][0],    Bb, n0,       0);
  STG(&BS[0][8192], Bb, n0 + 128, 0);
  STG(&AS[0][0],    Ab, m0,       0);
  STG(&AS[0][8192], Ab, m0 + 128, 0);
  STG(&BS[1][0],    Bb, n0,       64);
  STG(&BS[1][8192], Bb, n0 + 128, 64);
  VM4;                            // 12 units issued, retire 8 -> buf0 landed
  __builtin_amdgcn_s_barrier();

  for (int j = 0; j < 7; ++j) {
    const int kb = j * 128;
    PH2(0, 0, NOP,
        STG(&AS[1][0],    Ab, m0,       kb + 64);
        STG(&AS[1][8192], Ab, m0 + 128, kb + 64));
    PH2(0, 2, VM4,
        STG(&BS[0][0],    Bb, n0,       kb + 128);
        STG(&BS[0][8192], Bb, n0 + 128, kb + 128));
    PH2(1, 0, NOP,
        STG(&AS[0][0],    Ab, m0,       kb + 128);
        STG(&AS[0][8192], Ab, m0 + 128, kb + 128));
    PH2(1, 2, VM4,
        STG(&BS[1][0],    Bb, n0,       kb + 192);
        STG(&BS[1][8192], Bb, n0 + 128, kb + 192));
  }
  // tail: buf0 = tile@896 (landed via j=6 ph4 VM4), buf1 = tile@960
  PH2(0, 0, NOP,
      STG(&AS[1][0],    Ab, m0,       960);
      STG(&AS[1][8192], Ab, m0 + 128, 960));
  PH2(0, 2, VM0, NOP);            // drain: buf1 (A@960 + B@960) landed
  PH2(1, 0, NOP, NOP);
  PH2(1, 2, NOP, NOP);

#undef STG
#undef PH2
#undef VM4
#undef VM0
#undef NOP

  // epilogue: C/D layout col=lane&15, row=(lane>>4)*4+qq; scale by 1/rowsum[s]
#pragma unroll
  for (int mf = 0; mf < 8; ++mf) {
    f32x4 rsv = *(const f32x4*)&rsb[m0 + wr * 128 + mf * 16 + lq * 4];
    f32x4 inv;
#pragma unroll
    for (int qq = 0; qq < 4; ++qq) {
      float iv;
      asm("v_rcp_f32 %0, %1" : "=v"(iv) : "v"(rsv[qq]));
      inv[qq] = iv;
    }
#pragma unroll
    for (int nf = 0; nf < 4; ++nf) {
      int m = m0 + wr * 128 + mf * 16 + lq * 4;
      int n = n0 + wc * 64 + nf * 16 + lr;
#pragma unroll
      for (int qq = 0; qq < 4; ++qq)
        Cb[(size_t)(m + qq) * D_ + n] = acc[mf][nf][qq] * inv[qq];
    }
  }
}

// ---------------------------------------------------------------------------
// bf16 MFMA GEMM (128x128 tile, templated K-step BK) for G1/G2.
//   BK=64  (G1, K=768) / BK=128 (G2, K=128 -> single staged step).
// WT+OB16 epilogue: LDS-bounce to coalesced 256B row writes.
// EXPSUM (G2): atomic rowsums of rounded exp into Rs[n].
// XT (G1): also emit xt[d][t] bf16 via padded Ts transpose bounce.
// ---------------------------------------------------------------------------
template<int BK, bool BF32, bool TANH_, bool WT, bool OB16, bool EXPSUM, bool XT>
__global__ __launch_bounds__(256, 2)
void gemm_bt(const short* __restrict__ Ab, const void* __restrict__ Bv,
             void* __restrict__ Cv, float* __restrict__ Rs,
             short* __restrict__ Xt,
             int M, int N, int K,
             long sA, long sB, long sC, int gx, int gy) {
  constexpr int OPS = 128 * BK;                 // shorts per operand tile
  constexpr int BOUNCE = 128 * 136;             // epilogue bounce shorts
  constexpr int BASE = (2 * OPS > BOUNCE ? 2 * OPS : BOUNCE);
  __shared__ __align__(16) short SMEM[BASE + (XT ? 64 * 136 : 0)];
  short* As = SMEM;
  short* Bs = SMEM + OPS;
  short* Ts = SMEM + 2 * OPS;                   // XT only; disjoint from As/Bs

  unsigned nwg = gridDim.x;
  unsigned L = blockIdx.x;
  unsigned xcd = L & 7u, base = L >> 3;
  unsigned q = nwg >> 3, r = nwg & 7u;
  unsigned id = (xcd < r ? xcd * (q + 1) : r * (q + 1) + (xcd - r) * q) + base;
  const int gxy = gx * gy;
  const int bz = id / gxy;
  const int rem = id - bz * gxy;
  const int by = rem / gx;
  const int bx = rem - by * gx;

  const int tid = threadIdx.x;
  const int w = tid >> 6, lane = tid & 63;
  const int n0 = bx * 128, m0 = by * 128;
  const int wr = w >> 1, wc = w & 1;
  const int lr = lane & 15, lq = lane >> 4;
  const short* A = Ab + (size_t)sA * bz;
  const short* Bb16 = nullptr; const float* Bf32 = nullptr;
  if (BF32) Bf32 = (const float*)Bv + (size_t)sB * bz;
  else      Bb16 = (const short*)Bv + (size_t)sB * bz;
  short* Xtb = XT ? Xt + (size_t)bz * ((size_t)D_ * T_) : nullptr;

  f32x4 acc[4][4] = {};

  // gll16 staging geometry: 1KB chunk = 64 lanes x 16B
  constexpr int LPR = BK / 8;      // lanes per row
  constexpr int RPC = 64 / LPR;    // rows per chunk
  constexpr int CPT = BK / 16;     // chunks per wave per operand
  const int rl = lane / LPR;
  const int cl = (lane % LPR) * 8;

  for (int k0 = 0; k0 < K; k0 += BK) {
    __syncthreads();
#pragma unroll
    for (int i = 0; i < CPT; ++i) {
      int chunk = w * CPT + i;
      int row = chunk * RPC + rl;
      gll16(A + (size_t)(m0 + row) * K + k0 + cl, As + chunk * 512);
    }
    s16x8 parr[4];
    if (!BF32) {
#pragma unroll
      for (int i = 0; i < CPT; ++i) {
        int chunk = w * CPT + i;
        int row = chunk * RPC + rl;
        gll16(Bb16 + (size_t)(n0 + row) * K + k0 + cl, Bs + chunk * 512);
      }
    } else {
      // BK==64 reg-staged fp32->bf16 convert path
#pragma unroll
      for (int u = 0; u < 4; ++u) {
        int c = tid * 4 + u;
        int row = c >> 3, k8 = c & 7;
        const float* gp = Bf32 + (size_t)(n0 + row) * K + k0 + k8 * 8;
        float4 f0 = *(const float4*)gp;
        float4 f1 = *(const float4*)(gp + 4);
        s16x8 p;
        p[0] = f2b(f0.x); p[1] = f2b(f0.y); p[2] = f2b(f0.z); p[3] = f2b(f0.w);
        p[4] = f2b(f1.x); p[5] = f2b(f1.y); p[6] = f2b(f1.z); p[7] = f2b(f1.w);
        parr[u] = p;
        *(s16x8*)&Bs[row * 64 + k8 * 8] = p;
      }
    }
    __syncthreads();
#pragma unroll
    for (int kk = 0; kk < BK / 32; ++kk) {
      s16x8 a[4], b[4];
#pragma unroll
      for (int mf = 0; mf < 4; ++mf)
        a[mf] = *(const s16x8*)&As[(wr * 64 + mf * 16 + lr) * BK + kk * 32 + lq * 8];
#pragma unroll
      for (int nf = 0; nf < 4; ++nf)
        b[nf] = *(const s16x8*)&Bs[(wc * 64 + nf * 16 + lr) * BK + kk * 32 + lq * 8];
#pragma unroll
      for (int mf = 0; mf < 4; ++mf)
#pragma unroll
        for (int nf = 0; nf < 4; ++nf)
          acc[mf][nf] = __builtin_amdgcn_mfma_f32_16x16x32_bf16(
              a[mf], b[nf], acc[mf][nf], 0, 0, 0);
    }
    if constexpr (XT) {
      // transpose bounce: parr (x bf16, [t-local row][d-local k8*8+j]) -> Ts[d][t]
#pragma unroll
      for (int u = 0; u < 4; ++u) {
        int c = tid * 4 + u;
        int row = c >> 3, k8 = c & 7;
#pragma unroll
        for (int j = 0; j < 8; ++j) Ts[(k8 * 8 + j) * 136 + row] = parr[u][j];
      }
      __syncthreads();
      // coalesced xt write: 16 lanes cover one d-row's 128 t (256B)
#pragma unroll
      for (int u = 0; u < 4; ++u) {
        int task = tid + u * 256;          // 0..1023 = 64 d x 16 t8
        int dd = task >> 4, t8 = task & 15;
        *(s16x8*)&Xtb[(size_t)(k0 + dd) * T_ + n0 + t8 * 8] =
            *(const s16x8*)&Ts[dd * 136 + t8 * 8];
      }
    }
  }

  if (WT && OB16) {
    // ---- LDS-bounce transposed bf16 epilogue ----
    __syncthreads();                       // all waves done with As/Bs/Ts
    float psum[4] = {0.f, 0.f, 0.f, 0.f};
#pragma unroll
    for (int mf = 0; mf < 4; ++mf)
#pragma unroll
      for (int nf = 0; nf < 4; ++nf) {
        int ml = wr * 64 + mf * 16 + lq * 4;      // local m (col of row)
        int nl = wc * 64 + nf * 16 + lr;          // local n (row)
        s16x4 pk;
#pragma unroll
        for (int qq = 0; qq < 4; ++qq) {
          float v = acc[mf][nf][qq];
          if (TANH_) v = tanhf(v);
          if (EXPSUM) v = __expf(v);
          pk[qq] = f2b(v);
          if (EXPSUM) psum[nf] += b2f(pk[qq]);    // sum the ROUNDED values
        }
        *(s16x4*)&SMEM[nl * 136 + ml] = pk;
      }
    if (EXPSUM) {
      float* rs = Rs + (size_t)T_ * bz;
#pragma unroll
      for (int nf = 0; nf < 4; ++nf) {
        psum[nf] += __shfl_xor(psum[nf], 16);
        psum[nf] += __shfl_xor(psum[nf], 32);
      }
      if (lq == 0) {
#pragma unroll
        for (int nf = 0; nf < 4; ++nf)
          atomicAdd(&rs[n0 + wc * 64 + nf * 16 + lr], psum[nf]);
      }
    }
    __syncthreads();
    short* C = (short*)Cv + (size_t)sC * bz;
#pragma unroll
    for (int it = 0; it < 8; ++it) {
      int row = it * 16 + (tid >> 4);             // 0..127 (local n)
      int col = (tid & 15) * 8;                   // 0..120 (local m)
      *(s16x8*)(C + (size_t)(n0 + row) * M + m0 + col) =
          *(const s16x8*)&SMEM[row * 136 + col];
    }
  } else if (WT) {
    float* C = (float*)Cv + (size_t)sC * bz;
#pragma unroll
    for (int mf = 0; mf < 4; ++mf)
#pragma unroll
      for (int nf = 0; nf < 4; ++nf) {
        int mbase = m0 + wr * 64 + mf * 16 + lq * 4;
        int n = n0 + wc * 64 + nf * 16 + lr;
#pragma unroll
        for (int qq = 0; qq < 4; ++qq) {
          float v = acc[mf][nf][qq];
          if (TANH_) v = tanhf(v);
          C[(size_t)n * M + mbase + qq] = v;
        }
      }
  } else {
    float* C = (float*)Cv + (size_t)sC * bz;
#pragma unroll
    for (int mf = 0; mf < 4; ++mf)
#pragma unroll
      for (int nf = 0; nf < 4; ++nf) {
        int m = m0 + wr * 64 + mf * 16 + lq * 4;
        int n = n0 + wc * 64 + nf * 16 + lr;
#pragma unroll
        for (int qq = 0; qq < 4; ++qq) {
          float v = acc[mf][nf][qq];
          if (TANH_) v = tanhf(v);
          C[(size_t)(m + qq) * N + n] = v;
        }
      }
  }
}

// ---------------------------------------------------------------------------
// transpose + fp32->bf16 (W1/W2 only; x handled inside G1 via XT).
// ---------------------------------------------------------------------------
__global__ __launch_bounds__(256)
void transpose_cvt(const float* __restrict__ src, short* __restrict__ dst,
                   int R, int C) {
  __shared__ float sh[64][65];
  const int tid = threadIdx.x;
  const float* s = src + (size_t)blockIdx.z * R * C;
  short* d = dst + (size_t)blockIdx.z * R * C;
  const int r0 = blockIdx.y * 64, c0 = blockIdx.x * 64;
#pragma unroll
  for (int u = 0; u < 4; ++u) {
    int e = tid + u * 256;
    int rr = e >> 4, cc4 = (e & 15) * 4;
    float4 v = *(const float4*)&s[(size_t)(r0 + rr) * C + c0 + cc4];
    sh[rr][cc4 + 0] = v.x;
    sh[rr][cc4 + 1] = v.y;
    sh[rr][cc4 + 2] = v.z;
    sh[rr][cc4 + 3] = v.w;
  }
  __syncthreads();
#pragma unroll
  for (int u = 0; u < 4; ++u) {
    int e = tid + u * 256;
    int dr = e >> 4, tc4 = (e & 15) * 4;
    s16x4 pk;
#pragma unroll
    for (int j = 0; j < 4; ++j) pk[j] = f2b(sh[tc4 + j][dr]);
    *(s16x4*)&d[(size_t)(c0 + dr) * R + r0 + tc4] = pk;
  }
}

extern "C" void kernel_launch(void* const* d_in, const int* in_sizes, int n_in,
                              void* d_out, int out_size, void* d_ws, size_t ws_size,
                              hipStream_t stream) {
  const float* x  = (const float*)d_in[0];   // [B,T,D]
  const float* W1 = (const float*)d_in[1];   // [D,A]
  const float* W2 = (const float*)d_in[2];   // [A,T]
  float* out = (float*)d_out;                // [B,T,D] fp32

  // ws (shorts): xt[B,D,T] | W1t[A,D] | W2t[T,A] | H[B,T,A] | rs[B*T fp32] | St[nb,T,T]
  short* xt  = (short*)d_ws;
  short* W1t = xt + (size_t)B_ * D_ * T_;
  short* W2t = W1t + (size_t)A_ * D_;
  short* H   = W2t + (size_t)T_ * A_;
  float* rs  = (float*)(H + (size_t)B_ * T_ * A_);
  short* St  = (short*)(rs + (size_t)B_ * T_);
  size_t fixed_bytes = (size_t)((char*)St - (char*)xt);
  long avail = (long)ws_size - (long)fixed_bytes;
  long per_b = (long)T_ * T_ * sizeof(short);
  int chunk = (int)(avail > 0 ? avail / per_b : 0);
  if (chunk > B_) chunk = B_;
  if (chunk < 1) chunk = 1;

  // zero the rowsum accumulators (graph-capturable async memset)
  hipMemsetAsync(rs, 0, (size_t)B_ * T_ * sizeof(float), stream);

  // prep: transposed bf16 copies of the small weights only
  transpose_cvt<<<dim3(A_ / 64, D_ / 64, 1), 256, 0, stream>>>(W1, W1t, D_, A_);
  transpose_cvt<<<dim3(T_ / 64, A_ / 64, 1), 256, 0, stream>>>(W2, W2t, A_, T_);

  // G1: H^T = W1t @ x^T (M=A,N=T,K=D), tanh, transposed bf16 write -> H[t][a];
  //     ALSO emits xt[d][t] bf16 (XT path) from its x reg-staging.
  gemm_bt<64, true, true, true, true, false, true>
      <<<(T_ / 128) * (A_ / 128) * B_, 256, 0, stream>>>(
      W1t, x, H, nullptr, xt, A_, T_, D_, 0, (long)T_ * D_, (long)T_ * A_,
      T_ / 128, A_ / 128);

  for (int b0 = 0; b0 < B_; b0 += chunk) {
    int nb = B_ - b0; if (nb > chunk) nb = chunk;
    // G2: E[s,t] = exp(H @ W2t^T), single K=128 step, transposed bf16 write
    //     + rowsum atomics
    gemm_bt<128, false, false, true, true, true, false>
        <<<(T_ / 128) * (T_ / 128) * nb, 256, 0, stream>>>(
        H + (size_t)b0 * T_ * A_, W2t, St, rs + (size_t)b0 * T_, nullptr,
        T_, T_, A_, (long)T_ * A_, 0, (long)T_ * T_,
        T_ / 128, T_ / 128);
    // G4: out[s,d] = (E @ xt^T) / rowsum[s]
    g4_div<<<12 * nb, 512, 0, stream>>>(
        St, xt + (size_t)b0 * (size_t)D_ * T_, rs + (size_t)b0 * T_,
        out + (size_t)b0 * (size_t)T_ * D_);
  }
}

// Round 14
// 256.720 us; speedup vs baseline: 1.3236x; 1.1112x over previous
//
#include <hip/hip_runtime.h>
#include <math.h>

#define B_ 64
#define T_ 1024
#define D_ 768
#define A_ 128

typedef __attribute__((ext_vector_type(4))) float f32x4;
typedef __attribute__((ext_vector_type(8))) short s16x8;
typedef __attribute__((ext_vector_type(4))) short s16x4;

__device__ inline short f2b(float f) {
  union { float f; unsigned u; } v; v.f = f;
  unsigned r = (v.u + 0x7FFFu + ((v.u >> 16) & 1u)) >> 16;
  return (short)r;
}
__device__ inline float b2f(short s) {
  union { unsigned u; float f; } v; v.u = ((unsigned)(unsigned short)s) << 16;
  return v.f;
}

__device__ inline void gll16(const void* g, const void* lds) {
  __builtin_amdgcn_global_load_lds(
      (const __attribute__((address_space(1))) unsigned*)g,
      (__attribute__((address_space(3))) unsigned*)lds, 16, 0, 0);
}

// ---------------------------------------------------------------------------
// G4: 256x256-tile, BK=64, 8-wave, fused 4-phase counted-vmcnt bf16 GEMM
// (R13 version, best measured 133us). out[s,d]=(sum_t E[s,t]*xt[d,t])/rs[s].
// ---------------------------------------------------------------------------
__global__ __launch_bounds__(512, 2)
void g4_div(const short* __restrict__ Ag, const short* __restrict__ Bg,
            const float* __restrict__ Rs, float* __restrict__ Cg) {
  __shared__ __align__(16) short AS[2][16384];
  __shared__ __align__(16) short BS[2][16384];
  unsigned nwg = gridDim.x;
  unsigned L = blockIdx.x;
  unsigned xcd = L & 7u, base = L >> 3;
  unsigned q = nwg >> 3, r = nwg & 7u;
  unsigned id = (xcd < r ? xcd * (q + 1) : r * (q + 1) + (xcd - r) * q) + base;
  const int bz = id / 12;
  const int rem = id - bz * 12;
  const int by = rem / 3, bx = rem - (rem / 3) * 3;
  const int m0 = by * 256, n0 = bx * 256;

  const short* Ab = Ag + (size_t)bz * (T_ * T_);
  const short* Bb = Bg + (size_t)bz * (D_ * T_);
  const float* rsb = Rs + (size_t)bz * T_;
  float* Cb = Cg + (size_t)bz * (T_ * D_);

  const int tid = threadIdx.x;
  const int w = tid >> 6, lane = tid & 63;
  const int wr = w >> 2, wc = w & 3;
  const int lr = lane & 15, lq = lane >> 4;
  const int swzk = (lane & 7) ^ ((lane >> 3) & 7);
  const int abase = (wr * 128 + lr) * 64;
  const int bbase = (wc * 64 + lr) * 64;
  const int sx = lr & 7;
  const int sl0 = (lq ^ sx) * 8;
  const int sl1 = ((4 + lq) ^ sx) * 8;

  f32x4 acc[8][4] = {};
  s16x8 bq[4][2];

#define STG(dst, src, r0, kt)                                                  \
  { _Pragma("unroll")                                                          \
    for (int jj = 0; jj < 2; ++jj) {                                           \
      int rr = jj * 64 + w * 8 + (lane >> 3);                                  \
      gll16((src) + (size_t)((r0) + rr) * 1024 + (kt) + swzk * 8,              \
            (dst) + jj * 4096 + w * 512);                                      \
    } }

#define PH2(P, Q0, VM, ...)                                                    \
  {                                                                            \
    s16x8 a0_ = *(const s16x8*)&AS[P][abase + (2 * (Q0)) * 1024 + sl0];        \
    s16x8 a1_ = *(const s16x8*)&AS[P][abase + (2 * (Q0)) * 1024 + sl1];        \
    s16x8 a2_ = *(const s16x8*)&AS[P][abase + (2 * (Q0) + 1) * 1024 + sl0];    \
    s16x8 a3_ = *(const s16x8*)&AS[P][abase + (2 * (Q0) + 1) * 1024 + sl1];    \
    if ((Q0) == 0) {                                                           \
      _Pragma("unroll")                                                        \
      for (int nf = 0; nf < 4; ++nf) {                                         \
        bq[nf][0] = *(const s16x8*)&BS[P][bbase + nf * 1024 + sl0];            \
        bq[nf][1] = *(const s16x8*)&BS[P][bbase + nf * 1024 + sl1];            \
      }                                                                        \
    }                                                                          \
    __VA_ARGS__;                                                               \
    VM;                                                                        \
    __builtin_amdgcn_s_barrier();                                              \
    asm volatile("s_waitcnt lgkmcnt(0)" ::: "memory");                         \
    __builtin_amdgcn_s_setprio(1);                                             \
    _Pragma("unroll")                                                          \
    for (int nf = 0; nf < 4; ++nf) {                                           \
      acc[2*(Q0)][nf]   = __builtin_amdgcn_mfma_f32_16x16x32_bf16(a0_, bq[nf][0], acc[2*(Q0)][nf], 0, 0, 0);   \
      acc[2*(Q0)+1][nf] = __builtin_amdgcn_mfma_f32_16x16x32_bf16(a2_, bq[nf][0], acc[2*(Q0)+1][nf], 0, 0, 0); \
    }                                                                          \
    s16x8 a4_ = *(const s16x8*)&AS[P][abase + (2 * (Q0) + 2) * 1024 + sl0];    \
    s16x8 a5_ = *(const s16x8*)&AS[P][abase + (2 * (Q0) + 2) * 1024 + sl1];    \
    s16x8 a6_ = *(const s16x8*)&AS[P][abase + (2 * (Q0) + 3) * 1024 + sl0];    \
    s16x8 a7_ = *(const s16x8*)&AS[P][abase + (2 * (Q0) + 3) * 1024 + sl1];    \
    _Pragma("unroll")                                                          \
    for (int nf = 0; nf < 4; ++nf) {                                           \
      acc[2*(Q0)][nf]   = __builtin_amdgcn_mfma_f32_16x16x32_bf16(a1_, bq[nf][1], acc[2*(Q0)][nf], 0, 0, 0);   \
      acc[2*(Q0)+1][nf] = __builtin_amdgcn_mfma_f32_16x16x32_bf16(a3_, bq[nf][1], acc[2*(Q0)+1][nf], 0, 0, 0); \
    }                                                                          \
    _Pragma("unroll")                                                          \
    for (int nf = 0; nf < 4; ++nf) {                                           \
      acc[2*(Q0)+2][nf] = __builtin_amdgcn_mfma_f32_16x16x32_bf16(a4_, bq[nf][0], acc[2*(Q0)+2][nf], 0, 0, 0); \
      acc[2*(Q0)+3][nf] = __builtin_amdgcn_mfma_f32_16x16x32_bf16(a6_, bq[nf][0], acc[2*(Q0)+3][nf], 0, 0, 0); \
    }                                                                          \
    _Pragma("unroll")                                                          \
    for (int nf = 0; nf < 4; ++nf) {                                           \
      acc[2*(Q0)+2][nf] = __builtin_amdgcn_mfma_f32_16x16x32_bf16(a5_, bq[nf][1], acc[2*(Q0)+2][nf], 0, 0, 0); \
      acc[2*(Q0)+3][nf] = __builtin_amdgcn_mfma_f32_16x16x32_bf16(a7_, bq[nf][1], acc[2*(Q0)+3][nf], 0, 0, 0); \
    }                                                                          \
    __builtin_amdgcn_s_setprio(0);                                             \
    __builtin_amdgcn_s_barrier();                                              \
  }

#define VM4 asm volatile("s_waitcnt vmcnt(4)" ::: "memory")
#define VM0 asm volatile("s_waitcnt vmcnt(0)" ::: "memory")
#define NOP (void)0

  STG(&BS[0][0],    Bb, n0,       0);
  STG(&BS[0][8192], Bb, n0 + 128, 0);
  STG(&AS[0][0],    Ab, m0,       0);
  STG(&AS[0][8192], Ab, m0 + 128, 0);
  STG(&BS[1][0],    Bb, n0,       64);
  STG(&BS[1][8192], Bb, n0 + 128, 64);
  VM4;
  __builtin_amdgcn_s_barrier();

  for (int j = 0; j < 7; ++j) {
    const int kb = j * 128;
    PH2(0, 0, NOP,
        STG(&AS[1][0],    Ab, m0,       kb + 64);
        STG(&AS[1][8192], Ab, m0 + 128, kb + 64));
    PH2(0, 2, VM4,
        STG(&BS[0][0],    Bb, n0,       kb + 128);
        STG(&BS[0][8192], Bb, n0 + 128, kb + 128));
    PH2(1, 0, NOP,
        STG(&AS[0][0],    Ab, m0,       kb + 128);
        STG(&AS[0][8192], Ab, m0 + 128, kb + 128));
    PH2(1, 2, VM4,
        STG(&BS[1][0],    Bb, n0,       kb + 192);
        STG(&BS[1][8192], Bb, n0 + 128, kb + 192));
  }
  PH2(0, 0, NOP,
      STG(&AS[1][0],    Ab, m0,       960);
      STG(&AS[1][8192], Ab, m0 + 128, 960));
  PH2(0, 2, VM0, NOP);
  PH2(1, 0, NOP, NOP);
  PH2(1, 2, NOP, NOP);

#undef STG
#undef PH2
#undef VM4
#undef VM0
#undef NOP

#pragma unroll
  for (int mf = 0; mf < 8; ++mf) {
    f32x4 rsv = *(const f32x4*)&rsb[m0 + wr * 128 + mf * 16 + lq * 4];
    f32x4 inv;
#pragma unroll
    for (int qq = 0; qq < 4; ++qq) {
      float iv;
      asm("v_rcp_f32 %0, %1" : "=v"(iv) : "v"(rsv[qq]));
      inv[qq] = iv;
    }
#pragma unroll
    for (int nf = 0; nf < 4; ++nf) {
      int m = m0 + wr * 128 + mf * 16 + lq * 4;
      int n = n0 + wc * 64 + nf * 16 + lr;
#pragma unroll
      for (int qq = 0; qq < 4; ++qq)
        Cb[(size_t)(m + qq) * D_ + n] = acc[mf][nf][qq] * inv[qq];
    }
  }
}

// ---------------------------------------------------------------------------
// g12: FUSED G1+G2 per (t-tile, batch). 256 thr (4 waves), 2 blocks/CU.
// Main loop (= old G1): Ht-panel = tanh(W1t @ x^T) for 128 t rows, K=D=768,
//   BK=64; x reg-staged fp32->bf16 (parr) + XT bounce emits xt[d][t].
// Main epilogue: H -> LDS Hs[128t][128a], XOR-swizzled 16B slots (2-way
//   banked), NO global H round-trip.
// s-loop (= old G2, 8 iters): reg-stage W2t s-panel into swizzled B2;
//   64 MFMA (conflict-free frag reads on BOTH operands — old G2 was 16-way);
//   exp + rowsum atomics + bounce -> coalesced St[s][t] write.
// LDS: As[0,8K)+Bs[8K,16K)+Ts[16K,25K) shorts in main; Hs[0,16K) post-main;
//   B2/bounce [16K,33.7K). Total 66KB -> 2 blocks/CU; 512 blocks co-resident.
// ---------------------------------------------------------------------------
__global__ __launch_bounds__(256, 2)
void g12(const short* __restrict__ W1tg, const float* __restrict__ xg,
         const short* __restrict__ W2tg, short* __restrict__ Stg,
         float* __restrict__ rsg, short* __restrict__ xtg, int nb) {
  __shared__ __align__(16) short SMEM[33792];
  short* As = SMEM;            // main: W1t tile [128a][64k]
  short* Bs = SMEM + 8192;     // main: x-conv tile [128t][64k]
  short* Ts = SMEM + 16384;    // main XT bounce [64][136]
  short* Hs = SMEM;            // post-main: H [128t][128a] swizzled slots
  short* B2 = SMEM + 16384;    // s-loop: W2t [128s][128a] swizzled / St bounce [128][136]

  // bijective XCD swizzle
  unsigned nwg = gridDim.x;
  unsigned L = blockIdx.x;
  unsigned xcd = L & 7u, base = L >> 3;
  unsigned q = nwg >> 3, r = nwg & 7u;
  unsigned id = (xcd < r ? xcd * (q + 1) : r * (q + 1) + (xcd - r) * q) + base;
  const int bz = id >> 3, bt = id & 7;
  const int t0 = bt * 128;

  const float* xb = xg + (size_t)bz * T_ * D_;
  short* Xtb = xtg + (size_t)bz * ((size_t)D_ * T_);
  short* Stb = Stg + (size_t)bz * (T_ * T_);
  float* rsb = rsg + (size_t)bz * T_;

  const int tid = threadIdx.x;
  const int w = tid >> 6, lane = tid & 63;
  const int wr = w >> 1, wc = w & 1;
  const int lr = lane & 15, lq = lane >> 4;
  const int r8 = lane >> 3, c8 = lane & 7;

  f32x4 acc[4][4] = {};

  // ---------------- main loop: H^T = W1t @ x^T, 12 K-steps ----------------
  for (int k0 = 0; k0 < D_; k0 += 64) {
    __syncthreads();
#pragma unroll
    for (int i = 0; i < 4; ++i) {
      int chunk = w * 4 + i;
      int row = chunk * 8 + r8;          // a-row 0..127
      gll16(W1tg + (size_t)row * D_ + k0 + c8 * 8, As + chunk * 512);
    }
    s16x8 parr[4];
#pragma unroll
    for (int u = 0; u < 4; ++u) {
      int c = tid * 4 + u;
      int row = c >> 3, k8 = c & 7;      // t-local row, k-chunk
      const float* gp = xb + (size_t)(t0 + row) * D_ + k0 + k8 * 8;
      float4 f0 = *(const float4*)gp;
      float4 f1 = *(const float4*)(gp + 4);
      s16x8 p;
      p[0] = f2b(f0.x); p[1] = f2b(f0.y); p[2] = f2b(f0.z); p[3] = f2b(f0.w);
      p[4] = f2b(f1.x); p[5] = f2b(f1.y); p[6] = f2b(f1.z); p[7] = f2b(f1.w);
      parr[u] = p;
      *(s16x8*)&Bs[row * 64 + k8 * 8] = p;
    }
    __syncthreads();
#pragma unroll
    for (int kk = 0; kk < 2; ++kk) {
      s16x8 a[4], b[4];
#pragma unroll
      for (int mf = 0; mf < 4; ++mf)
        a[mf] = *(const s16x8*)&As[(wr * 64 + mf * 16 + lr) * 64 + kk * 32 + lq * 8];
#pragma unroll
      for (int nf = 0; nf < 4; ++nf)
        b[nf] = *(const s16x8*)&Bs[(wc * 64 + nf * 16 + lr) * 64 + kk * 32 + lq * 8];
#pragma unroll
      for (int mf = 0; mf < 4; ++mf)
#pragma unroll
        for (int nf = 0; nf < 4; ++nf)
          acc[mf][nf] = __builtin_amdgcn_mfma_f32_16x16x32_bf16(
              a[mf], b[nf], acc[mf][nf], 0, 0, 0);
    }
    // XT bounce: parr -> Ts[d][t] -> coalesced xt write
#pragma unroll
    for (int u = 0; u < 4; ++u) {
      int c = tid * 4 + u;
      int row = c >> 3, k8 = c & 7;
#pragma unroll
      for (int j = 0; j < 8; ++j) Ts[(k8 * 8 + j) * 136 + row] = parr[u][j];
    }
    __syncthreads();
#pragma unroll
    for (int u = 0; u < 4; ++u) {
      int task = tid + u * 256;
      int dd = task >> 4, t8 = task & 15;
      *(s16x8*)&Xtb[(size_t)(k0 + dd) * T_ + t0 + t8 * 8] =
          *(const s16x8*)&Ts[dd * 136 + t8 * 8];
    }
  }

  // ---- main epilogue: tanh(acc) -> Hs[t][a], swizzled 16B slots ----
  __syncthreads();
#pragma unroll
  for (int mf = 0; mf < 4; ++mf)
#pragma unroll
    for (int nf = 0; nf < 4; ++nf) {
      int ml = wr * 64 + mf * 16 + lq * 4;     // a (col)
      int nl = wc * 64 + nf * 16 + lr;         // t-local (row)
      s16x4 pk;
#pragma unroll
      for (int qq = 0; qq < 4; ++qq) pk[qq] = f2b(tanhf(acc[mf][nf][qq]));
      int slot = (ml >> 3) ^ (nl & 7);
      *(s16x4*)&Hs[nl * 128 + (slot << 3) + (ml & 7)] = pk;
    }
  __syncthreads();

  // ---------------- s-loop: E = exp(H @ W2t^T), 8 s-tiles ----------------
  const int sxl = lr & 7;
  for (int si = 0; si < 8; ++si) {
    const int s0 = si * 128;
    // stage W2t panel [128s][128a] into B2, swizzled slots
#pragma unroll
    for (int u = 0; u < 8; ++u) {
      int idx = tid + u * 256;
      int row = idx >> 4, c16 = idx & 15;
      *(s16x8*)&B2[row * 128 + ((c16 ^ (row & 7)) << 3)] =
          *(const s16x8*)&W2tg[(size_t)(s0 + row) * A_ + c16 * 8];
    }
    __syncthreads();
    // MFMA K=128
    f32x4 ac2[4][4] = {};
#pragma unroll
    for (int kk = 0; kk < 4; ++kk) {
      s16x8 a[4], b[4];
#pragma unroll
      for (int mf = 0; mf < 4; ++mf) {
        int row = wr * 64 + mf * 16 + lr;
        a[mf] = *(const s16x8*)&Hs[row * 128 + (((kk * 4 + lq) ^ sxl) << 3)];
      }
#pragma unroll
      for (int nf = 0; nf < 4; ++nf) {
        int row = wc * 64 + nf * 16 + lr;
        b[nf] = *(const s16x8*)&B2[row * 128 + (((kk * 4 + lq) ^ sxl) << 3)];
      }
#pragma unroll
      for (int mf = 0; mf < 4; ++mf)
#pragma unroll
        for (int nf = 0; nf < 4; ++nf)
          ac2[mf][nf] = __builtin_amdgcn_mfma_f32_16x16x32_bf16(
              a[mf], b[nf], ac2[mf][nf], 0, 0, 0);
    }
    __syncthreads();                       // B2 reads done; safe to overwrite
    // exp + psum + bounce into B2 ([128 s][136] layout)
    float psum[4] = {0.f, 0.f, 0.f, 0.f};
#pragma unroll
    for (int mf = 0; mf < 4; ++mf)
#pragma unroll
      for (int nf = 0; nf < 4; ++nf) {
        int ml = wr * 64 + mf * 16 + lq * 4;   // t-local (col)
        int nl = wc * 64 + nf * 16 + lr;       // s-local (row)
        s16x4 pk;
#pragma unroll
        for (int qq = 0; qq < 4; ++qq) {
          float v = __expf(ac2[mf][nf][qq]);
          pk[qq] = f2b(v);
          psum[nf] += b2f(pk[qq]);             // sum the ROUNDED values
        }
        *(s16x4*)&B2[nl * 136 + ml] = pk;
      }
#pragma unroll
    for (int nf = 0; nf < 4; ++nf) {
      psum[nf] += __shfl_xor(psum[nf], 16);
      psum[nf] += __shfl_xor(psum[nf], 32);
    }
    if (lq == 0) {
#pragma unroll
      for (int nf = 0; nf < 4; ++nf)
        atomicAdd(&rsb[s0 + wc * 64 + nf * 16 + lr], psum[nf]);
    }
    __syncthreads();
    // coalesced St write: rows s, 256B t-segments
#pragma unroll
    for (int it = 0; it < 8; ++it) {
      int row = it * 16 + (tid >> 4);
      int col = (tid & 15) * 8;
      *(s16x8*)&Stb[(size_t)(s0 + row) * T_ + t0 + col] =
          *(const s16x8*)&B2[row * 136 + col];
    }
    __syncthreads();                       // St-bounce reads done before restage
  }
}

// ---------------------------------------------------------------------------
// transpose + fp32->bf16 (W1/W2 only).
// ---------------------------------------------------------------------------
__global__ __launch_bounds__(256)
void transpose_cvt(const float* __restrict__ src, short* __restrict__ dst,
                   int R, int C) {
  __shared__ float sh[64][65];
  const int tid = threadIdx.x;
  const float* s = src + (size_t)blockIdx.z * R * C;
  short* d = dst + (size_t)blockIdx.z * R * C;
  const int r0 = blockIdx.y * 64, c0 = blockIdx.x * 64;
#pragma unroll
  for (int u = 0; u < 4; ++u) {
    int e = tid + u * 256;
    int rr = e >> 4, cc4 = (e & 15) * 4;
    float4 v = *(const float4*)&s[(size_t)(r0 + rr) * C + c0 + cc4];
    sh[rr][cc4 + 0] = v.x;
    sh[rr][cc4 + 1] = v.y;
    sh[rr][cc4 + 2] = v.z;
    sh[rr][cc4 + 3] = v.w;
  }
  __syncthreads();
#pragma unroll
  for (int u = 0; u < 4; ++u) {
    int e = tid + u * 256;
    int dr = e >> 4, tc4 = (e & 15) * 4;
    s16x4 pk;
#pragma unroll
    for (int j = 0; j < 4; ++j) pk[j] = f2b(sh[tc4 + j][dr]);
    *(s16x4*)&d[(size_t)(c0 + dr) * R + r0 + tc4] = pk;
  }
}

extern "C" void kernel_launch(void* const* d_in, const int* in_sizes, int n_in,
                              void* d_out, int out_size, void* d_ws, size_t ws_size,
                              hipStream_t stream) {
  const float* x  = (const float*)d_in[0];   // [B,T,D]
  const float* W1 = (const float*)d_in[1];   // [D,A]
  const float* W2 = (const float*)d_in[2];   // [A,T]
  float* out = (float*)d_out;                // [B,T,D] fp32

  // ws (shorts): xt[B,D,T] | W1t[A,D] | W2t[T,A] | rs[B*T fp32] | St[nb,T,T]
  short* xt  = (short*)d_ws;
  short* W1t = xt + (size_t)B_ * D_ * T_;
  short* W2t = W1t + (size_t)A_ * D_;
  float* rs  = (float*)(W2t + (size_t)T_ * A_);
  short* St  = (short*)(rs + (size_t)B_ * T_);
  size_t fixed_bytes = (size_t)((char*)St - (char*)xt);
  long avail = (long)ws_size - (long)fixed_bytes;
  long per_b = (long)T_ * T_ * sizeof(short);
  int chunk = (int)(avail > 0 ? avail / per_b : 0);
  if (chunk > B_) chunk = B_;
  if (chunk < 1) chunk = 1;

  // zero the rowsum accumulators (graph-capturable async memset)
  hipMemsetAsync(rs, 0, (size_t)B_ * T_ * sizeof(float), stream);

  // prep: transposed bf16 copies of the small weights
  transpose_cvt<<<dim3(A_ / 64, D_ / 64, 1), 256, 0, stream>>>(W1, W1t, D_, A_);
  transpose_cvt<<<dim3(T_ / 64, A_ / 64, 1), 256, 0, stream>>>(W2, W2t, A_, T_);

  for (int b0 = 0; b0 < B_; b0 += chunk) {
    int nb = B_ - b0; if (nb > chunk) nb = chunk;
    // g12 (fused G1+G2): per (t-tile, batch) block computes H in LDS, emits
    // xt, then E=exp(H@W2t^T) -> St + rowsum atomics. H never touches HBM.
    g12<<<8 * nb, 256, 0, stream>>>(
        W1t, x + (size_t)b0 * T_ * D_, W2t, St,
        rs + (size_t)b0 * T_, xt + (size_t)b0 * (size_t)D_ * T_, nb);
    // G4: out[s,d] = (E @ xt^T) / rowsum[s]
    g4_div<<<12 * nb, 512, 0, stream>>>(
        St, xt + (size_t)b0 * (size_t)D_ * T_, rs + (size_t)b0 * T_,
        out + (size_t)b0 * (size_t)T_ * D_);
  }
}

// Round 15
// 252.637 us; speedup vs baseline: 1.3449x; 1.0162x over previous
//
#include <hip/hip_runtime.h>
#include <math.h>

#define B_ 64
#define T_ 1024
#define D_ 768
#define A_ 128

typedef __attribute__((ext_vector_type(4))) float f32x4;
typedef __attribute__((ext_vector_type(8))) short s16x8;
typedef __attribute__((ext_vector_type(4))) short s16x4;

__device__ inline short f2b(float f) {
  union { float f; unsigned u; } v; v.f = f;
  unsigned r = (v.u + 0x7FFFu + ((v.u >> 16) & 1u)) >> 16;
  return (short)r;
}
__device__ inline float b2f(short s) {
  union { unsigned u; float f; } v; v.u = ((unsigned)(unsigned short)s) << 16;
  return v.f;
}

__device__ inline void gll16(const void* g, const void* lds) {
  __builtin_amdgcn_global_load_lds(
      (const __attribute__((address_space(1))) unsigned*)g,
      (__attribute__((address_space(3))) unsigned*)lds, 16, 0, 0);
}

// ---------------------------------------------------------------------------
// G4: 256x256-tile, BK=64, 8-wave, fused 4-phase counted-vmcnt bf16 GEMM
// (R13 version, best measured 133us). out[s,d]=(sum_t E[s,t]*xt[d,t])/rs[s].
// ---------------------------------------------------------------------------
__global__ __launch_bounds__(512, 2)
void g4_div(const short* __restrict__ Ag, const short* __restrict__ Bg,
            const float* __restrict__ Rs, float* __restrict__ Cg) {
  __shared__ __align__(16) short AS[2][16384];
  __shared__ __align__(16) short BS[2][16384];
  unsigned nwg = gridDim.x;
  unsigned L = blockIdx.x;
  unsigned xcd = L & 7u, base = L >> 3;
  unsigned q = nwg >> 3, r = nwg & 7u;
  unsigned id = (xcd < r ? xcd * (q + 1) : r * (q + 1) + (xcd - r) * q) + base;
  const int bz = id / 12;
  const int rem = id - bz * 12;
  const int by = rem / 3, bx = rem - (rem / 3) * 3;
  const int m0 = by * 256, n0 = bx * 256;

  const short* Ab = Ag + (size_t)bz * (T_ * T_);
  const short* Bb = Bg + (size_t)bz * (D_ * T_);
  const float* rsb = Rs + (size_t)bz * T_;
  float* Cb = Cg + (size_t)bz * (T_ * D_);

  const int tid = threadIdx.x;
  const int w = tid >> 6, lane = tid & 63;
  const int wr = w >> 2, wc = w & 3;
  const int lr = lane & 15, lq = lane >> 4;
  const int swzk = (lane & 7) ^ ((lane >> 3) & 7);
  const int abase = (wr * 128 + lr) * 64;
  const int bbase = (wc * 64 + lr) * 64;
  const int sx = lr & 7;
  const int sl0 = (lq ^ sx) * 8;
  const int sl1 = ((4 + lq) ^ sx) * 8;

  f32x4 acc[8][4] = {};
  s16x8 bq[4][2];

#define STG(dst, src, r0, kt)                                                  \
  { _Pragma("unroll")                                                          \
    for (int jj = 0; jj < 2; ++jj) {                                           \
      int rr = jj * 64 + w * 8 + (lane >> 3);                                  \
      gll16((src) + (size_t)((r0) + rr) * 1024 + (kt) + swzk * 8,              \
            (dst) + jj * 4096 + w * 512);                                      \
    } }

#define PH2(P, Q0, VM, ...)                                                    \
  {                                                                            \
    s16x8 a0_ = *(const s16x8*)&AS[P][abase + (2 * (Q0)) * 1024 + sl0];        \
    s16x8 a1_ = *(const s16x8*)&AS[P][abase + (2 * (Q0)) * 1024 + sl1];        \
    s16x8 a2_ = *(const s16x8*)&AS[P][abase + (2 * (Q0) + 1) * 1024 + sl0];    \
    s16x8 a3_ = *(const s16x8*)&AS[P][abase + (2 * (Q0) + 1) * 1024 + sl1];    \
    if ((Q0) == 0) {                                                           \
      _Pragma("unroll")                                                        \
      for (int nf = 0; nf < 4; ++nf) {                                         \
        bq[nf][0] = *(const s16x8*)&BS[P][bbase + nf * 1024 + sl0];            \
        bq[nf][1] = *(const s16x8*)&BS[P][bbase + nf * 1024 + sl1];            \
      }                                                                        \
    }                                                                          \
    __VA_ARGS__;                                                               \
    VM;                                                                        \
    __builtin_amdgcn_s_barrier();                                              \
    asm volatile("s_waitcnt lgkmcnt(0)" ::: "memory");                         \
    __builtin_amdgcn_s_setprio(1);                                             \
    _Pragma("unroll")                                                          \
    for (int nf = 0; nf < 4; ++nf) {                                           \
      acc[2*(Q0)][nf]   = __builtin_amdgcn_mfma_f32_16x16x32_bf16(a0_, bq[nf][0], acc[2*(Q0)][nf], 0, 0, 0);   \
      acc[2*(Q0)+1][nf] = __builtin_amdgcn_mfma_f32_16x16x32_bf16(a2_, bq[nf][0], acc[2*(Q0)+1][nf], 0, 0, 0); \
    }                                                                          \
    s16x8 a4_ = *(const s16x8*)&AS[P][abase + (2 * (Q0) + 2) * 1024 + sl0];    \
    s16x8 a5_ = *(const s16x8*)&AS[P][abase + (2 * (Q0) + 2) * 1024 + sl1];    \
    s16x8 a6_ = *(const s16x8*)&AS[P][abase + (2 * (Q0) + 3) * 1024 + sl0];    \
    s16x8 a7_ = *(const s16x8*)&AS[P][abase + (2 * (Q0) + 3) * 1024 + sl1];    \
    _Pragma("unroll")                                                          \
    for (int nf = 0; nf < 4; ++nf) {                                           \
      acc[2*(Q0)][nf]   = __builtin_amdgcn_mfma_f32_16x16x32_bf16(a1_, bq[nf][1], acc[2*(Q0)][nf], 0, 0, 0);   \
      acc[2*(Q0)+1][nf] = __builtin_amdgcn_mfma_f32_16x16x32_bf16(a3_, bq[nf][1], acc[2*(Q0)+1][nf], 0, 0, 0); \
    }                                                                          \
    _Pragma("unroll")                                                          \
    for (int nf = 0; nf < 4; ++nf) {                                           \
      acc[2*(Q0)+2][nf] = __builtin_amdgcn_mfma_f32_16x16x32_bf16(a4_, bq[nf][0], acc[2*(Q0)+2][nf], 0, 0, 0); \
      acc[2*(Q0)+3][nf] = __builtin_amdgcn_mfma_f32_16x16x32_bf16(a6_, bq[nf][0], acc[2*(Q0)+3][nf], 0, 0, 0); \
    }                                                                          \
    _Pragma("unroll")                                                          \
    for (int nf = 0; nf < 4; ++nf) {                                           \
      acc[2*(Q0)+2][nf] = __builtin_amdgcn_mfma_f32_16x16x32_bf16(a5_, bq[nf][1], acc[2*(Q0)+2][nf], 0, 0, 0); \
      acc[2*(Q0)+3][nf] = __builtin_amdgcn_mfma_f32_16x16x32_bf16(a7_, bq[nf][1], acc[2*(Q0)+3][nf], 0, 0, 0); \
    }                                                                          \
    __builtin_amdgcn_s_setprio(0);                                             \
    __builtin_amdgcn_s_barrier();                                              \
  }

#define VM4 asm volatile("s_waitcnt vmcnt(4)" ::: "memory")
#define VM0 asm volatile("s_waitcnt vmcnt(0)" ::: "memory")
#define NOP (void)0

  STG(&BS[0][0],    Bb, n0,       0);
  STG(&BS[0][8192], Bb, n0 + 128, 0);
  STG(&AS[0][0],    Ab, m0,       0);
  STG(&AS[0][8192], Ab, m0 + 128, 0);
  STG(&BS[1][0],    Bb, n0,       64);
  STG(&BS[1][8192], Bb, n0 + 128, 64);
  VM4;
  __builtin_amdgcn_s_barrier();

  for (int j = 0; j < 7; ++j) {
    const int kb = j * 128;
    PH2(0, 0, NOP,
        STG(&AS[1][0],    Ab, m0,       kb + 64);
        STG(&AS[1][8192], Ab, m0 + 128, kb + 64));
    PH2(0, 2, VM4,
        STG(&BS[0][0],    Bb, n0,       kb + 128);
        STG(&BS[0][8192], Bb, n0 + 128, kb + 128));
    PH2(1, 0, NOP,
        STG(&AS[0][0],    Ab, m0,       kb + 128);
        STG(&AS[0][8192], Ab, m0 + 128, kb + 128));
    PH2(1, 2, VM4,
        STG(&BS[1][0],    Bb, n0,       kb + 192);
        STG(&BS[1][8192], Bb, n0 + 128, kb + 192));
  }
  PH2(0, 0, NOP,
      STG(&AS[1][0],    Ab, m0,       960);
      STG(&AS[1][8192], Ab, m0 + 128, 960));
  PH2(0, 2, VM0, NOP);
  PH2(1, 0, NOP, NOP);
  PH2(1, 2, NOP, NOP);

#undef STG
#undef PH2
#undef VM4
#undef VM0
#undef NOP

#pragma unroll
  for (int mf = 0; mf < 8; ++mf) {
    f32x4 rsv = *(const f32x4*)&rsb[m0 + wr * 128 + mf * 16 + lq * 4];
    f32x4 inv;
#pragma unroll
    for (int qq = 0; qq < 4; ++qq) {
      float iv;
      asm("v_rcp_f32 %0, %1" : "=v"(iv) : "v"(rsv[qq]));
      inv[qq] = iv;
    }
#pragma unroll
    for (int nf = 0; nf < 4; ++nf) {
      int m = m0 + wr * 128 + mf * 16 + lq * 4;
      int n = n0 + wc * 64 + nf * 16 + lr;
#pragma unroll
      for (int qq = 0; qq < 4; ++qq)
        Cb[(size_t)(m + qq) * D_ + n] = acc[mf][nf][qq] * inv[qq];
    }
  }
}

// ---------------------------------------------------------------------------
// g12: FUSED G1+G2 per (t-tile, batch). 256 thr, 2 blocks/CU. R15 rework:
//  * x fp32 PREFETCH: next K-step's float4s loaded right after the stage
//    barrier -> retire at next top barrier (latency hidden under MFMA+xt).
//  * 2 barriers per main K-step (Ts written pre-stage-barrier; xt write in
//    the MFMA phase).
//  * As: pre-swizzled gll16 source + sl-swizzled reads (g4's proven pair).
//    Bs: direct swizzled writes. Kills the inherited 16-way frag conflicts.
//  * Ts transpose: col ^ (d&32) — XOR by 32 shorts = 64B shifts bank halves
//    (XOR <32 shorts stays in the same 16-bank set; >=32 required).
//  * W2t s-loop staging via gll16 with pre-swizzled per-lane SOURCE
//    (dest linear, rule #21) — no reg round-trip.
// ---------------------------------------------------------------------------
__global__ __launch_bounds__(256, 2)
void g12(const short* __restrict__ W1tg, const float* __restrict__ xg,
         const short* __restrict__ W2tg, short* __restrict__ Stg,
         float* __restrict__ rsg, short* __restrict__ xtg, int nb) {
  __shared__ __align__(16) short SMEM[33792];
  short* As = SMEM;            // main: W1t tile [128a][64k] slot-swizzled
  short* Bs = SMEM + 8192;     // main: x tile [128t][64k] slot-swizzled
  short* Ts = SMEM + 16384;    // main XT bounce [64d][136] (^32 col swizzle)
  short* Hs = SMEM;            // post-main: H [128t][128a] swizzled slots
  short* B2 = SMEM + 16384;    // s-loop: W2t swizzled / St bounce [128][136]

  // bijective XCD swizzle
  unsigned nwg = gridDim.x;
  unsigned L = blockIdx.x;
  unsigned xcd = L & 7u, base = L >> 3;
  unsigned q = nwg >> 3, r = nwg & 7u;
  unsigned id = (xcd < r ? xcd * (q + 1) : r * (q + 1) + (xcd - r) * q) + base;
  const int bz = id >> 3, bt = id & 7;
  const int t0 = bt * 128;

  const float* xb = xg + (size_t)bz * T_ * D_;
  short* Xtb = xtg + (size_t)bz * ((size_t)D_ * T_);
  short* Stb = Stg + (size_t)bz * (T_ * T_);
  float* rsb = rsg + (size_t)bz * T_;

  const int tid = threadIdx.x;
  const int w = tid >> 6, lane = tid & 63;
  const int wr = w >> 1, wc = w & 1;
  const int lr = lane & 15, lq = lane >> 4;
  const int swzk = (lane & 7) ^ ((lane >> 3) & 7);
  const int sxl = lr & 7;
  const int sl0 = (lq ^ sxl) * 8;          // BK=64 kk=0 swizzled slot
  const int sl1 = ((4 + lq) ^ sxl) * 8;    // kk=1

  f32x4 acc[4][4] = {};

  // ---- x prefetch registers (task u: c=tid*4+u -> trow=c>>3, k8=c&7) ----
  float4 xf0[4], xf1[4];
#pragma unroll
  for (int u = 0; u < 4; ++u) {
    int c = tid * 4 + u;
    int row = c >> 3, k8 = c & 7;
    const float* gp = xb + (size_t)(t0 + row) * D_ + k8 * 8;
    xf0[u] = *(const float4*)gp;
    xf1[u] = *(const float4*)(gp + 4);
  }

  // ---------------- main loop: H^T = W1t @ x^T, 12 K-steps ----------------
  for (int k0 = 0; k0 < D_; k0 += 64) {
    __syncthreads();                 // prev-iter reads done; xf loads landed
    // convert xf -> Bs (swizzled slots) + Ts (d-major, ^32 col swizzle)
#pragma unroll
    for (int u = 0; u < 4; ++u) {
      int c = tid * 4 + u;
      int row = c >> 3, k8 = c & 7;
      s16x8 p;
      p[0] = f2b(xf0[u].x); p[1] = f2b(xf0[u].y);
      p[2] = f2b(xf0[u].z); p[3] = f2b(xf0[u].w);
      p[4] = f2b(xf1[u].x); p[5] = f2b(xf1[u].y);
      p[6] = f2b(xf1[u].z); p[7] = f2b(xf1[u].w);
      *(s16x8*)&Bs[row * 64 + ((k8 ^ (row & 7)) << 3)] = p;
#pragma unroll
      for (int j = 0; j < 8; ++j) {
        int d = k8 * 8 + j;
        Ts[d * 136 + (row ^ (d & 32))] = p[j];
      }
    }
    // stage W1t tile via gll16, pre-swizzled source (g4's proven pair)
#pragma unroll
    for (int i = 0; i < 4; ++i) {
      int chunk = w * 4 + i;
      int row = chunk * 8 + (lane >> 3);
      gll16(W1tg + (size_t)row * D_ + k0 + swzk * 8, As + chunk * 512);
    }
    __syncthreads();                 // stage visible (vmcnt+lgkm drained)
    // prefetch next x tile — retires at next top barrier
    if (k0 + 64 < D_) {
#pragma unroll
      for (int u = 0; u < 4; ++u) {
        int c = tid * 4 + u;
        int row = c >> 3, k8 = c & 7;
        const float* gp = xb + (size_t)(t0 + row) * D_ + (k0 + 64) + k8 * 8;
        xf0[u] = *(const float4*)gp;
        xf1[u] = *(const float4*)(gp + 4);
      }
    }
    // MFMA (swizzled fragment reads — conflict-free)
#pragma unroll
    for (int kk = 0; kk < 2; ++kk) {
      const int sl = kk ? sl1 : sl0;
      s16x8 a[4], b[4];
#pragma unroll
      for (int mf = 0; mf < 4; ++mf)
        a[mf] = *(const s16x8*)&As[(wr * 64 + mf * 16 + lr) * 64 + sl];
#pragma unroll
      for (int nf = 0; nf < 4; ++nf)
        b[nf] = *(const s16x8*)&Bs[(wc * 64 + nf * 16 + lr) * 64 + sl];
#pragma unroll
      for (int mf = 0; mf < 4; ++mf)
#pragma unroll
        for (int nf = 0; nf < 4; ++nf)
          acc[mf][nf] = __builtin_amdgcn_mfma_f32_16x16x32_bf16(
              a[mf], b[nf], acc[mf][nf], 0, 0, 0);
    }
    // xt write from Ts (reads complete by next top barrier's lgkm drain)
#pragma unroll
    for (int u = 0; u < 4; ++u) {
      int task = tid + u * 256;
      int dd = task >> 4, t8 = task & 15;
      *(s16x8*)&Xtb[(size_t)(k0 + dd) * T_ + t0 + t8 * 8] =
          *(const s16x8*)&Ts[dd * 136 + ((t8 ^ ((dd >> 3) & 4)) << 3)];
    }
  }

  // ---- main epilogue: tanh(acc) -> Hs[t][a], swizzled 16B slots ----
  __syncthreads();
#pragma unroll
  for (int mf = 0; mf < 4; ++mf)
#pragma unroll
    for (int nf = 0; nf < 4; ++nf) {
      int ml = wr * 64 + mf * 16 + lq * 4;     // a (col)
      int nl = wc * 64 + nf * 16 + lr;         // t-local (row)
      s16x4 pk;
#pragma unroll
      for (int qq = 0; qq < 4; ++qq) pk[qq] = f2b(tanhf(acc[mf][nf][qq]));
      int slot = (ml >> 3) ^ (nl & 7);
      *(s16x4*)&Hs[nl * 128 + (slot << 3) + (ml & 7)] = pk;
    }
  __syncthreads();

  // ---------------- s-loop: E = exp(H @ W2t^T), 8 s-tiles ----------------
  for (int si = 0; si < 8; ++si) {
    const int s0 = si * 128;
    // stage W2t panel via gll16 with pre-swizzled per-lane source
#pragma unroll
    for (int i = 0; i < 8; ++i) {
      int c = w * 8 + i;
      int row = 4 * c + (lane >> 4);
      gll16(W2tg + (size_t)(s0 + row) * A_ + (((lane & 15) ^ (row & 7)) << 3),
            B2 + c * 512);
    }
    __syncthreads();
    // MFMA K=128
    f32x4 ac2[4][4] = {};
#pragma unroll
    for (int kk = 0; kk < 4; ++kk) {
      s16x8 a[4], b[4];
#pragma unroll
      for (int mf = 0; mf < 4; ++mf) {
        int row = wr * 64 + mf * 16 + lr;
        a[mf] = *(const s16x8*)&Hs[row * 128 + (((kk * 4 + lq) ^ sxl) << 3)];
      }
#pragma unroll
      for (int nf = 0; nf < 4; ++nf) {
        int row = wc * 64 + nf * 16 + lr;
        b[nf] = *(const s16x8*)&B2[row * 128 + (((kk * 4 + lq) ^ sxl) << 3)];
      }
#pragma unroll
      for (int mf = 0; mf < 4; ++mf)
#pragma unroll
        for (int nf = 0; nf < 4; ++nf)
          ac2[mf][nf] = __builtin_amdgcn_mfma_f32_16x16x32_bf16(
              a[mf], b[nf], ac2[mf][nf], 0, 0, 0);
    }
    __syncthreads();                       // B2 reads done; safe to overwrite
    // exp + psum + bounce into B2 ([128 s][136] layout)
    float psum[4] = {0.f, 0.f, 0.f, 0.f};
#pragma unroll
    for (int mf = 0; mf < 4; ++mf)
#pragma unroll
      for (int nf = 0; nf < 4; ++nf) {
        int ml = wr * 64 + mf * 16 + lq * 4;   // t-local (col)
        int nl = wc * 64 + nf * 16 + lr;       // s-local (row)
        s16x4 pk;
#pragma unroll
        for (int qq = 0; qq < 4; ++qq) {
          float v = __expf(ac2[mf][nf][qq]);
          pk[qq] = f2b(v);
          psum[nf] += b2f(pk[qq]);             // sum the ROUNDED values
        }
        *(s16x4*)&B2[nl * 136 + ml] = pk;
      }
#pragma unroll
    for (int nf = 0; nf < 4; ++nf) {
      psum[nf] += __shfl_xor(psum[nf], 16);
      psum[nf] += __shfl_xor(psum[nf], 32);
    }
    if (lq == 0) {
#pragma unroll
      for (int nf = 0; nf < 4; ++nf)
        atomicAdd(&rsb[s0 + wc * 64 + nf * 16 + lr], psum[nf]);
    }
    __syncthreads();
    // coalesced St write: rows s, 256B t-segments
#pragma unroll
    for (int it = 0; it < 8; ++it) {
      int row = it * 16 + (tid >> 4);
      int col = (tid & 15) * 8;
      *(s16x8*)&Stb[(size_t)(s0 + row) * T_ + t0 + col] =
          *(const s16x8*)&B2[row * 136 + col];
    }
    __syncthreads();                       // St-bounce reads done before restage
  }
}

// ---------------------------------------------------------------------------
// transpose + fp32->bf16 (W1/W2 only).
// ---------------------------------------------------------------------------
__global__ __launch_bounds__(256)
void transpose_cvt(const float* __restrict__ src, short* __restrict__ dst,
                   int R, int C) {
  __shared__ float sh[64][65];
  const int tid = threadIdx.x;
  const float* s = src + (size_t)blockIdx.z * R * C;
  short* d = dst + (size_t)blockIdx.z * R * C;
  const int r0 = blockIdx.y * 64, c0 = blockIdx.x * 64;
#pragma unroll
  for (int u = 0; u < 4; ++u) {
    int e = tid + u * 256;
    int rr = e >> 4, cc4 = (e & 15) * 4;
    float4 v = *(const float4*)&s[(size_t)(r0 + rr) * C + c0 + cc4];
    sh[rr][cc4 + 0] = v.x;
    sh[rr][cc4 + 1] = v.y;
    sh[rr][cc4 + 2] = v.z;
    sh[rr][cc4 + 3] = v.w;
  }
  __syncthreads();
#pragma unroll
  for (int u = 0; u < 4; ++u) {
    int e = tid + u * 256;
    int dr = e >> 4, tc4 = (e & 15) * 4;
    s16x4 pk;
#pragma unroll
    for (int j = 0; j < 4; ++j) pk[j] = f2b(sh[tc4 + j][dr]);
    *(s16x4*)&d[(size_t)(c0 + dr) * R + r0 + tc4] = pk;
  }
}

extern "C" void kernel_launch(void* const* d_in, const int* in_sizes, int n_in,
                              void* d_out, int out_size, void* d_ws, size_t ws_size,
                              hipStream_t stream) {
  const float* x  = (const float*)d_in[0];   // [B,T,D]
  const float* W1 = (const float*)d_in[1];   // [D,A]
  const float* W2 = (const float*)d_in[2];   // [A,T]
  float* out = (float*)d_out;                // [B,T,D] fp32

  // ws (shorts): xt[B,D,T] | W1t[A,D] | W2t[T,A] | rs[B*T fp32] | St[nb,T,T]
  short* xt  = (short*)d_ws;
  short* W1t = xt + (size_t)B_ * D_ * T_;
  short* W2t = W1t + (size_t)A_ * D_;
  float* rs  = (float*)(W2t + (size_t)T_ * A_);
  short* St  = (short*)(rs + (size_t)B_ * T_);
  size_t fixed_bytes = (size_t)((char*)St - (char*)xt);
  long avail = (long)ws_size - (long)fixed_bytes;
  long per_b = (long)T_ * T_ * sizeof(short);
  int chunk = (int)(avail > 0 ? avail / per_b : 0);
  if (chunk > B_) chunk = B_;
  if (chunk < 1) chunk = 1;

  // zero the rowsum accumulators (graph-capturable async memset)
  hipMemsetAsync(rs, 0, (size_t)B_ * T_ * sizeof(float), stream);

  // prep: transposed bf16 copies of the small weights
  transpose_cvt<<<dim3(A_ / 64, D_ / 64, 1), 256, 0, stream>>>(W1, W1t, D_, A_);
  transpose_cvt<<<dim3(T_ / 64, A_ / 64, 1), 256, 0, stream>>>(W2, W2t, A_, T_);

  for (int b0 = 0; b0 < B_; b0 += chunk) {
    int nb = B_ - b0; if (nb > chunk) nb = chunk;
    // g12 (fused G1+G2): per (t-tile, batch) block computes H in LDS, emits
    // xt, then E=exp(H@W2t^T) -> St + rowsum atomics. H never touches HBM.
    g12<<<8 * nb, 256, 0, stream>>>(
        W1t, x + (size_t)b0 * T_ * D_, W2t, St,
        rs + (size_t)b0 * T_, xt + (size_t)b0 * (size_t)D_ * T_, nb);
    // G4: out[s,d] = (E @ xt^T) / rowsum[s]
    g4_div<<<12 * nb, 512, 0, stream>>>(
        St, xt + (size_t)b0 * (size_t)D_ * T_, rs + (size_t)b0 * T_,
        out + (size_t)b0 * (size_t)T_ * D_);
  }
}

// Round 16
// 250.533 us; speedup vs baseline: 1.3562x; 1.0084x over previous
//
#include <hip/hip_runtime.h>
#include <math.h>

#define B_ 64
#define T_ 1024
#define D_ 768
#define A_ 128

typedef __attribute__((ext_vector_type(4))) float f32x4;
typedef __attribute__((ext_vector_type(8))) short s16x8;
typedef __attribute__((ext_vector_type(4))) short s16x4;

__device__ inline short f2b(float f) {
  union { float f; unsigned u; } v; v.f = f;
  unsigned r = (v.u + 0x7FFFu + ((v.u >> 16) & 1u)) >> 16;
  return (short)r;
}
__device__ inline float b2f(short s) {
  union { unsigned u; float f; } v; v.u = ((unsigned)(unsigned short)s) << 16;
  return v.f;
}

__device__ inline void gll16(const void* g, const void* lds) {
  __builtin_amdgcn_global_load_lds(
      (const __attribute__((address_space(1))) unsigned*)g,
      (__attribute__((address_space(3))) unsigned*)lds, 16, 0, 0);
}

// ---------------------------------------------------------------------------
// G4: 256x256-tile, BK=64, 8-wave, fused 4-phase counted-vmcnt bf16 GEMM
// (R13 version). out[s,d]=(sum_t E[s,t]*xt[d,t])/rs[s].
// ---------------------------------------------------------------------------
__global__ __launch_bounds__(512, 2)
void g4_div(const short* __restrict__ Ag, const short* __restrict__ Bg,
            const float* __restrict__ Rs, float* __restrict__ Cg) {
  __shared__ __align__(16) short AS[2][16384];
  __shared__ __align__(16) short BS[2][16384];
  unsigned nwg = gridDim.x;
  unsigned L = blockIdx.x;
  unsigned xcd = L & 7u, base = L >> 3;
  unsigned q = nwg >> 3, r = nwg & 7u;
  unsigned id = (xcd < r ? xcd * (q + 1) : r * (q + 1) + (xcd - r) * q) + base;
  const int bz = id / 12;
  const int rem = id - bz * 12;
  const int by = rem / 3, bx = rem - (rem / 3) * 3;
  const int m0 = by * 256, n0 = bx * 256;

  const short* Ab = Ag + (size_t)bz * (T_ * T_);
  const short* Bb = Bg + (size_t)bz * (D_ * T_);
  const float* rsb = Rs + (size_t)bz * T_;
  float* Cb = Cg + (size_t)bz * (T_ * D_);

  const int tid = threadIdx.x;
  const int w = tid >> 6, lane = tid & 63;
  const int wr = w >> 2, wc = w & 3;
  const int lr = lane & 15, lq = lane >> 4;
  const int swzk = (lane & 7) ^ ((lane >> 3) & 7);
  const int abase = (wr * 128 + lr) * 64;
  const int bbase = (wc * 64 + lr) * 64;
  const int sx = lr & 7;
  const int sl0 = (lq ^ sx) * 8;
  const int sl1 = ((4 + lq) ^ sx) * 8;

  f32x4 acc[8][4] = {};
  s16x8 bq[4][2];

#define STG(dst, src, r0, kt)                                                  \
  { _Pragma("unroll")                                                          \
    for (int jj = 0; jj < 2; ++jj) {                                           \
      int rr = jj * 64 + w * 8 + (lane >> 3);                                  \
      gll16((src) + (size_t)((r0) + rr) * 1024 + (kt) + swzk * 8,              \
            (dst) + jj * 4096 + w * 512);                                      \
    } }

#define PH2(P, Q0, VM, ...)                                                    \
  {                                                                            \
    s16x8 a0_ = *(const s16x8*)&AS[P][abase + (2 * (Q0)) * 1024 + sl0];        \
    s16x8 a1_ = *(const s16x8*)&AS[P][abase + (2 * (Q0)) * 1024 + sl1];        \
    s16x8 a2_ = *(const s16x8*)&AS[P][abase + (2 * (Q0) + 1) * 1024 + sl0];    \
    s16x8 a3_ = *(const s16x8*)&AS[P][abase + (2 * (Q0) + 1) * 1024 + sl1];    \
    if ((Q0) == 0) {                                                           \
      _Pragma("unroll")                                                        \
      for (int nf = 0; nf < 4; ++nf) {                                         \
        bq[nf][0] = *(const s16x8*)&BS[P][bbase + nf * 1024 + sl0];            \
        bq[nf][1] = *(const s16x8*)&BS[P][bbase + nf * 1024 + sl1];            \
      }                                                                        \
    }                                                                          \
    __VA_ARGS__;                                                               \
    VM;                                                                        \
    __builtin_amdgcn_s_barrier();                                              \
    asm volatile("s_waitcnt lgkmcnt(0)" ::: "memory");                         \
    __builtin_amdgcn_s_setprio(1);                                             \
    _Pragma("unroll")                                                          \
    for (int nf = 0; nf < 4; ++nf) {                                           \
      acc[2*(Q0)][nf]   = __builtin_amdgcn_mfma_f32_16x16x32_bf16(a0_, bq[nf][0], acc[2*(Q0)][nf], 0, 0, 0);   \
      acc[2*(Q0)+1][nf] = __builtin_amdgcn_mfma_f32_16x16x32_bf16(a2_, bq[nf][0], acc[2*(Q0)+1][nf], 0, 0, 0); \
    }                                                                          \
    s16x8 a4_ = *(const s16x8*)&AS[P][abase + (2 * (Q0) + 2) * 1024 + sl0];    \
    s16x8 a5_ = *(const s16x8*)&AS[P][abase + (2 * (Q0) + 2) * 1024 + sl1];    \
    s16x8 a6_ = *(const s16x8*)&AS[P][abase + (2 * (Q0) + 3) * 1024 + sl0];    \
    s16x8 a7_ = *(const s16x8*)&AS[P][abase + (2 * (Q0) + 3) * 1024 + sl1];    \
    _Pragma("unroll")                                                          \
    for (int nf = 0; nf < 4; ++nf) {                                           \
      acc[2*(Q0)][nf]   = __builtin_amdgcn_mfma_f32_16x16x32_bf16(a1_, bq[nf][1], acc[2*(Q0)][nf], 0, 0, 0);   \
      acc[2*(Q0)+1][nf] = __builtin_amdgcn_mfma_f32_16x16x32_bf16(a3_, bq[nf][1], acc[2*(Q0)+1][nf], 0, 0, 0); \
    }                                                                          \
    _Pragma("unroll")                                                          \
    for (int nf = 0; nf < 4; ++nf) {                                           \
      acc[2*(Q0)+2][nf] = __builtin_amdgcn_mfma_f32_16x16x32_bf16(a4_, bq[nf][0], acc[2*(Q0)+2][nf], 0, 0, 0); \
      acc[2*(Q0)+3][nf] = __builtin_amdgcn_mfma_f32_16x16x32_bf16(a6_, bq[nf][0], acc[2*(Q0)+3][nf], 0, 0, 0); \
    }                                                                          \
    _Pragma("unroll")                                                          \
    for (int nf = 0; nf < 4; ++nf) {                                           \
      acc[2*(Q0)+2][nf] = __builtin_amdgcn_mfma_f32_16x16x32_bf16(a5_, bq[nf][1], acc[2*(Q0)+2][nf], 0, 0, 0); \
      acc[2*(Q0)+3][nf] = __builtin_amdgcn_mfma_f32_16x16x32_bf16(a7_, bq[nf][1], acc[2*(Q0)+3][nf], 0, 0, 0); \
    }                                                                          \
    __builtin_amdgcn_s_setprio(0);                                             \
    __builtin_amdgcn_s_barrier();                                              \
  }

#define VM4 asm volatile("s_waitcnt vmcnt(4)" ::: "memory")
#define VM0 asm volatile("s_waitcnt vmcnt(0)" ::: "memory")
#define NOP (void)0

  STG(&BS[0][0],    Bb, n0,       0);
  STG(&BS[0][8192], Bb, n0 + 128, 0);
  STG(&AS[0][0],    Ab, m0,       0);
  STG(&AS[0][8192], Ab, m0 + 128, 0);
  STG(&BS[1][0],    Bb, n0,       64);
  STG(&BS[1][8192], Bb, n0 + 128, 64);
  VM4;
  __builtin_amdgcn_s_barrier();

  for (int j = 0; j < 7; ++j) {
    const int kb = j * 128;
    PH2(0, 0, NOP,
        STG(&AS[1][0],    Ab, m0,       kb + 64);
        STG(&AS[1][8192], Ab, m0 + 128, kb + 64));
    PH2(0, 2, VM4,
        STG(&BS[0][0],    Bb, n0,       kb + 128);
        STG(&BS[0][8192], Bb, n0 + 128, kb + 128));
    PH2(1, 0, NOP,
        STG(&AS[0][0],    Ab, m0,       kb + 128);
        STG(&AS[0][8192], Ab, m0 + 128, kb + 128));
    PH2(1, 2, VM4,
        STG(&BS[1][0],    Bb, n0,       kb + 192);
        STG(&BS[1][8192], Bb, n0 + 128, kb + 192));
  }
  PH2(0, 0, NOP,
      STG(&AS[1][0],    Ab, m0,       960);
      STG(&AS[1][8192], Ab, m0 + 128, 960));
  PH2(0, 2, VM0, NOP);
  PH2(1, 0, NOP, NOP);
  PH2(1, 2, NOP, NOP);

#undef STG
#undef PH2
#undef VM4
#undef VM0
#undef NOP

#pragma unroll
  for (int mf = 0; mf < 8; ++mf) {
    f32x4 rsv = *(const f32x4*)&rsb[m0 + wr * 128 + mf * 16 + lq * 4];
    f32x4 inv;
#pragma unroll
    for (int qq = 0; qq < 4; ++qq) {
      float iv;
      asm("v_rcp_f32 %0, %1" : "=v"(iv) : "v"(rsv[qq]));
      inv[qq] = iv;
    }
#pragma unroll
    for (int nf = 0; nf < 4; ++nf) {
      int m = m0 + wr * 128 + mf * 16 + lq * 4;
      int n = n0 + wc * 64 + nf * 16 + lr;
#pragma unroll
      for (int qq = 0; qq < 4; ++qq)
        Cb[(size_t)(m + qq) * D_ + n] = acc[mf][nf][qq] * inv[qq];
    }
  }
}

// ---------------------------------------------------------------------------
// g12: FUSED G1+G2 per (t-tile, batch). R16: 512 threads / 8 WAVES per block
// (was 4) — same 512-block grid, LDS 66KB, 2 blocks/CU, so waves/CU doubles
// 8 -> 16 (occupancy 25% -> 50%). R15 showed g12 latency/sync-bound with
// NOTHING busy (Mfma 8%, VALU 20%, HBM 36%); more resident waves is the
// direct lever. Per-wave tiles halve: main acc[4][2] (a-half x t-quarter),
// s-loop ac2[4][2] (t-half x s-quarter). All swizzle pairs from the passing
// R15 kernel preserved. __launch_bounds__(512,4) caps VGPR at 128 (demand
// ~110, safe — R6 lesson checked).
// ---------------------------------------------------------------------------
__global__ __launch_bounds__(512, 4)
void g12(const short* __restrict__ W1tg, const float* __restrict__ xg,
         const short* __restrict__ W2tg, short* __restrict__ Stg,
         float* __restrict__ rsg, short* __restrict__ xtg, int nb) {
  __shared__ __align__(16) short SMEM[33792];
  short* As = SMEM;            // main: W1t tile [128a][64k] slot-swizzled
  short* Bs = SMEM + 8192;     // main: x tile [128t][64k] slot-swizzled
  short* Ts = SMEM + 16384;    // main XT bounce [64d][136] (^32 col swizzle)
  short* Hs = SMEM;            // post-main: H [128t][128a] swizzled slots
  short* B2 = SMEM + 16384;    // s-loop: W2t swizzled / St bounce [128][136]

  // bijective XCD swizzle
  unsigned nwg = gridDim.x;
  unsigned L = blockIdx.x;
  unsigned xcd = L & 7u, base = L >> 3;
  unsigned q = nwg >> 3, r = nwg & 7u;
  unsigned id = (xcd < r ? xcd * (q + 1) : r * (q + 1) + (xcd - r) * q) + base;
  const int bz = id >> 3, bt = id & 7;
  const int t0 = bt * 128;

  const float* xb = xg + (size_t)bz * T_ * D_;
  short* Xtb = xtg + (size_t)bz * ((size_t)D_ * T_);
  short* Stb = Stg + (size_t)bz * (T_ * T_);
  float* rsb = rsg + (size_t)bz * T_;

  const int tid = threadIdx.x;
  const int w = tid >> 6, lane = tid & 63;
  const int wva = w >> 2, wvt = w & 3;     // main: a-half, t-quarter
  const int lr = lane & 15, lq = lane >> 4;
  const int swzk = (lane & 7) ^ ((lane >> 3) & 7);
  const int sxl = lr & 7;
  const int sl0 = (lq ^ sxl) * 8;          // BK=64 kk=0 swizzled slot
  const int sl1 = ((4 + lq) ^ sxl) * 8;    // kk=1

  f32x4 acc[4][2] = {};

  // ---- x prefetch (task c = tid*2+u: trow=c>>3 (0..127), k8=c&7) ----
  float4 xf0[2], xf1[2];
#pragma unroll
  for (int u = 0; u < 2; ++u) {
    int c = tid * 2 + u;
    int row = c >> 3, k8 = c & 7;
    const float* gp = xb + (size_t)(t0 + row) * D_ + k8 * 8;
    xf0[u] = *(const float4*)gp;
    xf1[u] = *(const float4*)(gp + 4);
  }

  // ---------------- main loop: H^T = W1t @ x^T, 12 K-steps ----------------
  for (int k0 = 0; k0 < D_; k0 += 64) {
    __syncthreads();                 // prev-iter reads done; xf loads landed
    // convert xf -> Bs (swizzled slots) + Ts (d-major, ^32 col swizzle)
#pragma unroll
    for (int u = 0; u < 2; ++u) {
      int c = tid * 2 + u;
      int row = c >> 3, k8 = c & 7;
      s16x8 p;
      p[0] = f2b(xf0[u].x); p[1] = f2b(xf0[u].y);
      p[2] = f2b(xf0[u].z); p[3] = f2b(xf0[u].w);
      p[4] = f2b(xf1[u].x); p[5] = f2b(xf1[u].y);
      p[6] = f2b(xf1[u].z); p[7] = f2b(xf1[u].w);
      *(s16x8*)&Bs[row * 64 + ((k8 ^ (row & 7)) << 3)] = p;
#pragma unroll
      for (int j = 0; j < 8; ++j) {
        int d = k8 * 8 + j;
        Ts[d * 136 + (row ^ (d & 32))] = p[j];
      }
    }
    // stage W1t tile via gll16, pre-swizzled source
#pragma unroll
    for (int i = 0; i < 2; ++i) {
      int chunk = w * 2 + i;
      int row = chunk * 8 + (lane >> 3);
      gll16(W1tg + (size_t)row * D_ + k0 + swzk * 8, As + chunk * 512);
    }
    __syncthreads();                 // stage visible
    // prefetch next x tile
    if (k0 + 64 < D_) {
#pragma unroll
      for (int u = 0; u < 2; ++u) {
        int c = tid * 2 + u;
        int row = c >> 3, k8 = c & 7;
        const float* gp = xb + (size_t)(t0 + row) * D_ + (k0 + 64) + k8 * 8;
        xf0[u] = *(const float4*)gp;
        xf1[u] = *(const float4*)(gp + 4);
      }
    }
    // MFMA (swizzled fragment reads)
#pragma unroll
    for (int kk = 0; kk < 2; ++kk) {
      const int sl = kk ? sl1 : sl0;
      s16x8 a[4], b[2];
#pragma unroll
      for (int mf = 0; mf < 4; ++mf)
        a[mf] = *(const s16x8*)&As[(wva * 64 + mf * 16 + lr) * 64 + sl];
#pragma unroll
      for (int nf = 0; nf < 2; ++nf)
        b[nf] = *(const s16x8*)&Bs[(wvt * 32 + nf * 16 + lr) * 64 + sl];
#pragma unroll
      for (int mf = 0; mf < 4; ++mf)
#pragma unroll
        for (int nf = 0; nf < 2; ++nf)
          acc[mf][nf] = __builtin_amdgcn_mfma_f32_16x16x32_bf16(
              a[mf], b[nf], acc[mf][nf], 0, 0, 0);
    }
    // xt write from Ts
#pragma unroll
    for (int u = 0; u < 2; ++u) {
      int task = tid + u * 512;
      int dd = task >> 4, t8 = task & 15;
      *(s16x8*)&Xtb[(size_t)(k0 + dd) * T_ + t0 + t8 * 8] =
          *(const s16x8*)&Ts[dd * 136 + ((t8 ^ ((dd >> 3) & 4)) << 3)];
    }
  }

  // ---- main epilogue: tanh(acc) -> Hs[t][a], swizzled 16B slots ----
  __syncthreads();
#pragma unroll
  for (int mf = 0; mf < 4; ++mf)
#pragma unroll
    for (int nf = 0; nf < 2; ++nf) {
      int ml = wva * 64 + mf * 16 + lq * 4;    // a (col)
      int nl = wvt * 32 + nf * 16 + lr;        // t-local (row)
      s16x4 pk;
#pragma unroll
      for (int qq = 0; qq < 4; ++qq) pk[qq] = f2b(tanhf(acc[mf][nf][qq]));
      int slot = (ml >> 3) ^ (nl & 7);
      *(s16x4*)&Hs[nl * 128 + (slot << 3) + (ml & 7)] = pk;
    }
  __syncthreads();

  // ---------------- s-loop: E = exp(H @ W2t^T), 8 s-tiles ----------------
  const int wvt2 = w >> 2, wvs = w & 3;    // t-half, s-quarter
  for (int si = 0; si < 8; ++si) {
    const int s0 = si * 128;
    // stage W2t panel via gll16 with pre-swizzled per-lane source
#pragma unroll
    for (int i = 0; i < 4; ++i) {
      int c = w * 4 + i;
      int row = 4 * c + (lane >> 4);
      gll16(W2tg + (size_t)(s0 + row) * A_ + (((lane & 15) ^ (row & 7)) << 3),
            B2 + c * 512);
    }
    __syncthreads();
    // MFMA K=128
    f32x4 ac2[4][2] = {};
#pragma unroll
    for (int kk = 0; kk < 4; ++kk) {
      s16x8 a[4], b[2];
#pragma unroll
      for (int mf = 0; mf < 4; ++mf) {
        int row = wvt2 * 64 + mf * 16 + lr;
        a[mf] = *(const s16x8*)&Hs[row * 128 + (((kk * 4 + lq) ^ sxl) << 3)];
      }
#pragma unroll
      for (int nf = 0; nf < 2; ++nf) {
        int row = wvs * 32 + nf * 16 + lr;
        b[nf] = *(const s16x8*)&B2[row * 128 + (((kk * 4 + lq) ^ sxl) << 3)];
      }
#pragma unroll
      for (int mf = 0; mf < 4; ++mf)
#pragma unroll
        for (int nf = 0; nf < 2; ++nf)
          ac2[mf][nf] = __builtin_amdgcn_mfma_f32_16x16x32_bf16(
              a[mf], b[nf], ac2[mf][nf], 0, 0, 0);
    }
    __syncthreads();                       // B2 reads done; safe to overwrite
    // exp + psum + bounce into B2 ([128 s][136] layout)
    float psum[2] = {0.f, 0.f};
#pragma unroll
    for (int mf = 0; mf < 4; ++mf)
#pragma unroll
      for (int nf = 0; nf < 2; ++nf) {
        int ml = wvt2 * 64 + mf * 16 + lq * 4;  // t-local (col)
        int nl = wvs * 32 + nf * 16 + lr;       // s-local (row)
        s16x4 pk;
#pragma unroll
        for (int qq = 0; qq < 4; ++qq) {
          float v = __expf(ac2[mf][nf][qq]);
          pk[qq] = f2b(v);
          psum[nf] += b2f(pk[qq]);              // sum the ROUNDED values
        }
        *(s16x4*)&B2[nl * 136 + ml] = pk;
      }
#pragma unroll
    for (int nf = 0; nf < 2; ++nf) {
      psum[nf] += __shfl_xor(psum[nf], 16);
      psum[nf] += __shfl_xor(psum[nf], 32);
    }
    if (lq == 0) {
#pragma unroll
      for (int nf = 0; nf < 2; ++nf)
        atomicAdd(&rsb[s0 + wvs * 32 + nf * 16 + lr], psum[nf]);
    }
    __syncthreads();
    // coalesced St write: rows s, 256B t-segments
#pragma unroll
    for (int it = 0; it < 4; ++it) {
      int row = it * 32 + (tid >> 4);
      int col = (tid & 15) * 8;
      *(s16x8*)&Stb[(size_t)(s0 + row) * T_ + t0 + col] =
          *(const s16x8*)&B2[row * 136 + col];
    }
    __syncthreads();                       // St-bounce reads done before restage
  }
}

// ---------------------------------------------------------------------------
// transpose + fp32->bf16 (W1/W2 only).
// ---------------------------------------------------------------------------
__global__ __launch_bounds__(256)
void transpose_cvt(const float* __restrict__ src, short* __restrict__ dst,
                   int R, int C) {
  __shared__ float sh[64][65];
  const int tid = threadIdx.x;
  const float* s = src + (size_t)blockIdx.z * R * C;
  short* d = dst + (size_t)blockIdx.z * R * C;
  const int r0 = blockIdx.y * 64, c0 = blockIdx.x * 64;
#pragma unroll
  for (int u = 0; u < 4; ++u) {
    int e = tid + u * 256;
    int rr = e >> 4, cc4 = (e & 15) * 4;
    float4 v = *(const float4*)&s[(size_t)(r0 + rr) * C + c0 + cc4];
    sh[rr][cc4 + 0] = v.x;
    sh[rr][cc4 + 1] = v.y;
    sh[rr][cc4 + 2] = v.z;
    sh[rr][cc4 + 3] = v.w;
  }
  __syncthreads();
#pragma unroll
  for (int u = 0; u < 4; ++u) {
    int e = tid + u * 256;
    int dr = e >> 4, tc4 = (e & 15) * 4;
    s16x4 pk;
#pragma unroll
    for (int j = 0; j < 4; ++j) pk[j] = f2b(sh[tc4 + j][dr]);
    *(s16x4*)&d[(size_t)(c0 + dr) * R + r0 + tc4] = pk;
  }
}

extern "C" void kernel_launch(void* const* d_in, const int* in_sizes, int n_in,
                              void* d_out, int out_size, void* d_ws, size_t ws_size,
                              hipStream_t stream) {
  const float* x  = (const float*)d_in[0];   // [B,T,D]
  const float* W1 = (const float*)d_in[1];   // [D,A]
  const float* W2 = (const float*)d_in[2];   // [A,T]
  float* out = (float*)d_out;                // [B,T,D] fp32

  // ws (shorts): xt[B,D,T] | W1t[A,D] | W2t[T,A] | rs[B*T fp32] | St[nb,T,T]
  short* xt  = (short*)d_ws;
  short* W1t = xt + (size_t)B_ * D_ * T_;
  short* W2t = W1t + (size_t)A_ * D_;
  float* rs  = (float*)(W2t + (size_t)T_ * A_);
  short* St  = (short*)(rs + (size_t)B_ * T_);
  size_t fixed_bytes = (size_t)((char*)St - (char*)xt);
  long avail = (long)ws_size - (long)fixed_bytes;
  long per_b = (long)T_ * T_ * sizeof(short);
  int chunk = (int)(avail > 0 ? avail / per_b : 0);
  if (chunk > B_) chunk = B_;
  if (chunk < 1) chunk = 1;

  // zero the rowsum accumulators (graph-capturable async memset)
  hipMemsetAsync(rs, 0, (size_t)B_ * T_ * sizeof(float), stream);

  // prep: transposed bf16 copies of the small weights
  transpose_cvt<<<dim3(A_ / 64, D_ / 64, 1), 256, 0, stream>>>(W1, W1t, D_, A_);
  transpose_cvt<<<dim3(T_ / 64, A_ / 64, 1), 256, 0, stream>>>(W2, W2t, A_, T_);

  for (int b0 = 0; b0 < B_; b0 += chunk) {
    int nb = B_ - b0; if (nb > chunk) nb = chunk;
    // g12 (fused G1+G2): per (t-tile, batch) block computes H in LDS, emits
    // xt, then E=exp(H@W2t^T) -> St + rowsum atomics. H never touches HBM.
    g12<<<8 * nb, 512, 0, stream>>>(
        W1t, x + (size_t)b0 * T_ * D_, W2t, St,
        rs + (size_t)b0 * T_, xt + (size_t)b0 * (size_t)D_ * T_, nb);
    // G4: out[s,d] = (E @ xt^T) / rowsum[s]
    g4_div<<<12 * nb, 512, 0, stream>>>(
        St, xt + (size_t)b0 * (size_t)D_ * T_, rs + (size_t)b0 * T_,
        out + (size_t)b0 * (size_t)T_ * D_);
  }
}